// Round 1
// baseline (945.592 us; speedup 1.0000x reference)
//
#include <hip/hip_runtime.h>
#include <hip/hip_bf16.h>

#define BATCH 4096
#define SEQ 10
#define DIM 1024
#define TWOD 2048
#define HID 512

// ---------------- workspace layout (in floats) ----------------
// attx : BATCH*DIM        @ 0
// atty : BATCH*DIM        @ 4194304
// arow : BATCH*16         @ 8388608   (a[b,9,t], stride 16 per batch)
// stats: 32               @ 8454144   (m[0..9] at +0, Z[0..9] at +16)
// oc   : BATCH*2048       @ 8454176   (oc[b,0:1024]=o1, oc[b,1024:2048]=o2)
// h    : BATCH*512        @ 16842784
#define OFF_ATTX  0u
#define OFF_ATTY  4194304u
#define OFF_AROW  8388608u
#define OFF_STATS 8454144u
#define OFF_OC    8454176u
#define OFF_H     16842784u
// total 18,939,936 floats = 75.8 MB

// K1: per-batch — a_col9 softmax -> attx[b,:], and a_row9[b,:] raw scores
__global__ __launch_bounds__(256) void k_attn1(const float* __restrict__ X1,
                                               const float* __restrict__ X2,
                                               float* __restrict__ attx,
                                               float* __restrict__ arow) {
  int b = blockIdx.x;
  __shared__ float X1s[SEQ * DIM];   // 40 KB
  __shared__ float x29[DIM];         // 4 KB
  __shared__ float acol[SEQ], arw[SEQ];
  int tid = threadIdx.x;
  int lane = tid & 63, wave = tid >> 6;
  const float* x1b = X1 + (size_t)b * SEQ * DIM;
  const float* x2b = X2 + (size_t)b * SEQ * DIM;

  // stage X1[b] (10x1024) and X2[b,9,:]
  for (int i = tid * 4; i < SEQ * DIM; i += 1024)
    *(float4*)&X1s[i] = *(const float4*)&x1b[i];
  *(float4*)&x29[tid * 4] = *(const float4*)&x2b[9 * DIM + tid * 4];
  __syncthreads();

  // a_col9[s] = dot(X1[b,s,:], X2[b,9,:])
  for (int s = wave; s < SEQ; s += 4) {
    float p = 0.f;
    for (int k = lane; k < DIM; k += 64) p += X1s[s * DIM + k] * x29[k];
    for (int off = 32; off; off >>= 1) p += __shfl_down(p, off, 64);
    if (lane == 0) acol[s] = p;
  }
  // a_row9[t] = dot(X1[b,9,:], X2[b,t,:])
  for (int t = wave; t < SEQ; t += 4) {
    float p = 0.f;
    const float* x2t = x2b + t * DIM;
    for (int k = lane; k < DIM; k += 64) p += X1s[9 * DIM + k] * x2t[k];
    for (int off = 32; off; off >>= 1) p += __shfl_down(p, off, 64);
    if (lane == 0) arw[t] = p;
  }
  __syncthreads();
  if (tid < SEQ) arow[(size_t)b * 16 + tid] = arw[tid];

  // softmax over s (redundant per-thread, only 10 values)
  float m = -1e30f;
#pragma unroll
  for (int s = 0; s < SEQ; s++) m = fmaxf(m, acol[s]);
  float w[SEQ], Z = 0.f;
#pragma unroll
  for (int s = 0; s < SEQ; s++) { w[s] = __expf(acol[s] - m); Z += w[s]; }
  float inv = 1.f / Z;

  // attx[b,d] = sum_s w[s] * X1[b,s,d]
  for (int d = tid; d < DIM; d += 256) {
    float acc = 0.f;
#pragma unroll
    for (int s = 0; s < SEQ; s++) acc += w[s] * X1s[s * DIM + d];
    attx[(size_t)b * DIM + d] = acc * inv;
  }
}

// K2: cross-batch softmax stats per t: m_t = max_b, Z_t = sum_b exp(.-m_t)
__global__ __launch_bounds__(256) void k_stats(const float* __restrict__ arow,
                                               float* __restrict__ stats) {
  int t = blockIdx.x;
  int tid = threadIdx.x, lane = tid & 63, wave = tid >> 6;
  __shared__ float wred[4];
  float m = -1e30f;
  for (int b = tid; b < BATCH; b += 256) m = fmaxf(m, arow[(size_t)b * 16 + t]);
  for (int off = 32; off; off >>= 1) m = fmaxf(m, __shfl_down(m, off, 64));
  if (lane == 0) wred[wave] = m;
  __syncthreads();
  m = fmaxf(fmaxf(wred[0], wred[1]), fmaxf(wred[2], wred[3]));
  __syncthreads();
  float z = 0.f;
  for (int b = tid; b < BATCH; b += 256) z += __expf(arow[(size_t)b * 16 + t] - m);
  for (int off = 32; off; off >>= 1) z += __shfl_down(z, off, 64);
  if (lane == 0) wred[wave] = z;
  __syncthreads();
  if (tid == 0) {
    stats[t] = m;
    stats[16 + t] = wred[0] + wred[1] + wred[2] + wred[3];
  }
}

// K3: atty[b,d] = sum_t softmax_b(a_row9)[b,t] * X2[b,t,d]
__global__ __launch_bounds__(256) void k_atty(const float* __restrict__ X2,
                                              const float* __restrict__ arow,
                                              const float* __restrict__ stats,
                                              float* __restrict__ atty) {
  int b = blockIdx.x;
  int tid = threadIdx.x;
  __shared__ float wy[SEQ];
  if (tid < SEQ)
    wy[tid] = __expf(arow[(size_t)b * 16 + tid] - stats[tid]) / stats[16 + tid];
  __syncthreads();
  const float* x2b = X2 + (size_t)b * SEQ * DIM;
  for (int d = tid; d < DIM; d += 256) {
    float acc = 0.f;
#pragma unroll
    for (int t = 0; t < SEQ; t++) acc += wy[t] * x2b[t * DIM + d];
    atty[(size_t)b * DIM + d] = acc;
  }
}

// K4: oc[b, 0:1024]  = [X1[b,9,:] | atty[b,:]] @ Wg + bg
//     oc[b,1024:2048]= [X2[b,9,:] | attx[b,:]] @ Wg + bg
// 64x64 tile, BK=16, 256 threads, 4x4 per thread
__global__ __launch_bounds__(256) void k_gemm1(const float* __restrict__ X1,
                                               const float* __restrict__ X2,
                                               const float* __restrict__ attx,
                                               const float* __restrict__ atty,
                                               const float* __restrict__ Wg,
                                               const float* __restrict__ bg,
                                               float* __restrict__ oc) {
  __shared__ float As[16][68];  // padded: conflict-light, rows 16B aligned
  __shared__ float Bs[16][64];
  int nb = blockIdx.x, mb = blockIdx.y;
  bool second = nb >= 16;
  int n0 = (nb & 15) * 64;                    // weight column base
  int outcol0 = second ? 1024 + n0 : n0;      // output column base
  const float* Arow = second ? X2 : X1;
  const float* Aatt = second ? attx : atty;
  int tid = threadIdx.x;
  int tx = tid & 15, ty = tid >> 4;
  int la_m = tid >> 2, la_k = (tid & 3) * 4;  // A loader: row, k4
  int lb_k = tid >> 4, lb_n = (tid & 15) * 4; // B loader
  int m0 = mb * 64;
  float acc[4][4] = {};

  for (int k0 = 0; k0 < TWOD; k0 += 16) {
    int m = m0 + la_m;
    int k = k0 + la_k;
    float4 av;
    if (k < DIM) {
      av = *(const float4*)(Arow + ((size_t)m * SEQ + 9) * DIM + k);
    } else {
      av = *(const float4*)(Aatt + (size_t)m * DIM + (k - DIM));
    }
    As[la_k + 0][la_m] = av.x;
    As[la_k + 1][la_m] = av.y;
    As[la_k + 2][la_m] = av.z;
    As[la_k + 3][la_m] = av.w;
    *(float4*)&Bs[lb_k][lb_n] =
        *(const float4*)(Wg + (size_t)(k0 + lb_k) * DIM + n0 + lb_n);
    __syncthreads();
#pragma unroll
    for (int kk = 0; kk < 16; kk++) {
      float4 a = *(float4*)&As[kk][ty * 4];
      float4 bv = *(float4*)&Bs[kk][tx * 4];
      float ar[4] = {a.x, a.y, a.z, a.w};
      float br[4] = {bv.x, bv.y, bv.z, bv.w};
#pragma unroll
      for (int i = 0; i < 4; i++)
#pragma unroll
        for (int j = 0; j < 4; j++) acc[i][j] += ar[i] * br[j];
    }
    __syncthreads();
  }
#pragma unroll
  for (int i = 0; i < 4; i++) {
    int m = m0 + ty * 4 + i;
#pragma unroll
    for (int j = 0; j < 4; j++) {
      int c = tx * 4 + j;
      oc[(size_t)m * TWOD + outcol0 + c] = acc[i][j] + bg[n0 + c];
    }
  }
}

// K5: h = relu(oc @ Wfd + bfd), M=4096 K=2048 N=512
__global__ __launch_bounds__(256) void k_gemm2(const float* __restrict__ oc,
                                               const float* __restrict__ Wfd,
                                               const float* __restrict__ bfd,
                                               float* __restrict__ h) {
  __shared__ float As[16][68];
  __shared__ float Bs[16][64];
  int nb = blockIdx.x, mb = blockIdx.y;
  int n0 = nb * 64;
  int tid = threadIdx.x;
  int tx = tid & 15, ty = tid >> 4;
  int la_m = tid >> 2, la_k = (tid & 3) * 4;
  int lb_k = tid >> 4, lb_n = (tid & 15) * 4;
  int m0 = mb * 64;
  float acc[4][4] = {};

  for (int k0 = 0; k0 < TWOD; k0 += 16) {
    float4 av = *(const float4*)(oc + (size_t)(m0 + la_m) * TWOD + k0 + la_k);
    As[la_k + 0][la_m] = av.x;
    As[la_k + 1][la_m] = av.y;
    As[la_k + 2][la_m] = av.z;
    As[la_k + 3][la_m] = av.w;
    *(float4*)&Bs[lb_k][lb_n] =
        *(const float4*)(Wfd + (size_t)(k0 + lb_k) * HID + n0 + lb_n);
    __syncthreads();
#pragma unroll
    for (int kk = 0; kk < 16; kk++) {
      float4 a = *(float4*)&As[kk][ty * 4];
      float4 bv = *(float4*)&Bs[kk][tx * 4];
      float ar[4] = {a.x, a.y, a.z, a.w};
      float br[4] = {bv.x, bv.y, bv.z, bv.w};
#pragma unroll
      for (int i = 0; i < 4; i++)
#pragma unroll
        for (int j = 0; j < 4; j++) acc[i][j] += ar[i] * br[j];
    }
    __syncthreads();
  }
#pragma unroll
  for (int i = 0; i < 4; i++) {
    int m = m0 + ty * 4 + i;
#pragma unroll
    for (int j = 0; j < 4; j++) {
      int c = n0 + tx * 4 + j;
      float v = acc[i][j] + bfd[c];
      h[(size_t)m * HID + c] = v > 0.f ? v : 0.f;
    }
  }
}

// K6: out[b] = sigmoid(dot(h[b,:], Wff) + bff)
__global__ __launch_bounds__(256) void k_final(const float* __restrict__ h,
                                               const float* __restrict__ Wff,
                                               const float* __restrict__ bff,
                                               float* __restrict__ out) {
  int b = blockIdx.x * 4 + (threadIdx.x >> 6);
  int lane = threadIdx.x & 63;
  const float* hb = h + (size_t)b * HID;
  float p = 0.f;
#pragma unroll
  for (int j = lane; j < HID; j += 64) p += hb[j] * Wff[j];
  for (int off = 32; off; off >>= 1) p += __shfl_down(p, off, 64);
  if (lane == 0) out[b] = 1.f / (1.f + __expf(-(p + bff[0])));
}

extern "C" void kernel_launch(void* const* d_in, const int* in_sizes, int n_in,
                              void* d_out, int out_size, void* d_ws, size_t ws_size,
                              hipStream_t stream) {
  const float* X1  = (const float*)d_in[0];
  const float* X2  = (const float*)d_in[1];
  const float* Wg  = (const float*)d_in[2];
  const float* bg  = (const float*)d_in[3];
  const float* Wfd = (const float*)d_in[4];
  const float* bfd = (const float*)d_in[5];
  const float* Wff = (const float*)d_in[6];
  const float* bff = (const float*)d_in[7];
  float* out = (float*)d_out;
  float* ws = (float*)d_ws;

  float* attx  = ws + OFF_ATTX;
  float* atty  = ws + OFF_ATTY;
  float* arow  = ws + OFF_AROW;
  float* stats = ws + OFF_STATS;
  float* oc    = ws + OFF_OC;
  float* h     = ws + OFF_H;

  k_attn1<<<BATCH, 256, 0, stream>>>(X1, X2, attx, arow);
  k_stats<<<SEQ, 256, 0, stream>>>(arow, stats);
  k_atty<<<BATCH, 256, 0, stream>>>(X2, arow, stats, atty);
  k_gemm1<<<dim3(32, 64), 256, 0, stream>>>(X1, X2, attx, atty, Wg, bg, oc);
  k_gemm2<<<dim3(8, 64), 256, 0, stream>>>(oc, Wfd, bfd, h);
  k_final<<<BATCH / 4, 256, 0, stream>>>(h, Wff, bff, out);
}

// Round 2
// 343.791 us; speedup vs baseline: 2.7505x; 2.7505x over previous
//
#include <hip/hip_runtime.h>
#include <hip/hip_bf16.h>

#define BATCH 4096
#define SEQ 10
#define DIM 1024
#define TWOD 2048
#define HID 512

typedef __attribute__((ext_vector_type(8))) short bf16x8;
typedef __attribute__((ext_vector_type(4))) float f32x4;

// ---------------- workspace layout (bytes) ----------------
// Abf  : bf16 [8192][2048]  @ 0      (rows 0..4095 = [X1_9|atty], 4096.. = [X2_9|attx])
// ocb  : bf16 [4096][2048]  @ 32MB
// WgT  : bf16 [1024][2048]  @ 48MB
// WfdT : bf16 [512][2048]   @ 52MB
// h    : f32  [4096][512]   @ 54MB
// arow : f32  [4096*16]     @ 62MB
// stats: f32  [32]          @ 62.25MB
#define OFF_ABF   0ull
#define OFF_OCB   (32ull << 20)
#define OFF_WGT   (48ull << 20)
#define OFF_WFDT  (52ull << 20)
#define OFF_H     (54ull << 20)
#define OFF_AROW  (62ull << 20)
#define OFF_STATS (OFF_AROW + 4096ull * 16 * 4)

#define GLOAD_LDS16(g, l)                                                     \
  __builtin_amdgcn_global_load_lds(                                           \
      (const __attribute__((address_space(1))) unsigned int*)(g),             \
      (__attribute__((address_space(3))) unsigned int*)(l), 16, 0, 0)

// K1: per-batch — a_col9 softmax -> attx (bf16 into Abf), raw a_row9 scores,
// plus bf16 copies of X1[b,9,:] and X2[b,9,:] into Abf.
__global__ __launch_bounds__(256) void k_attn1(const float* __restrict__ X1,
                                               const float* __restrict__ X2,
                                               __hip_bfloat16* __restrict__ abf,
                                               float* __restrict__ arow) {
  int b = blockIdx.x;
  __shared__ float X1s[SEQ * DIM];
  __shared__ float x29[DIM];
  __shared__ float acol[SEQ], arw[SEQ];
  int tid = threadIdx.x;
  int lane = tid & 63, wave = tid >> 6;
  const float* x1b = X1 + (size_t)b * SEQ * DIM;
  const float* x2b = X2 + (size_t)b * SEQ * DIM;

  for (int i = tid * 4; i < SEQ * DIM; i += 1024)
    *(float4*)&X1s[i] = *(const float4*)&x1b[i];
  *(float4*)&x29[tid * 4] = *(const float4*)&x2b[9 * DIM + tid * 4];
  __syncthreads();

  for (int s = wave; s < SEQ; s += 4) {
    float p = 0.f;
    for (int k = lane; k < DIM; k += 64) p += X1s[s * DIM + k] * x29[k];
    for (int off = 32; off; off >>= 1) p += __shfl_down(p, off, 64);
    if (lane == 0) acol[s] = p;
  }
  for (int t = wave; t < SEQ; t += 4) {
    float p = 0.f;
    const float* x2t = x2b + t * DIM;
    for (int k = lane; k < DIM; k += 64) p += X1s[9 * DIM + k] * x2t[k];
    for (int off = 32; off; off >>= 1) p += __shfl_down(p, off, 64);
    if (lane == 0) arw[t] = p;
  }
  __syncthreads();
  if (tid < SEQ) arow[(size_t)b * 16 + tid] = arw[tid];

  float m = -1e30f;
#pragma unroll
  for (int s = 0; s < SEQ; s++) m = fmaxf(m, acol[s]);
  float w[SEQ], Z = 0.f;
#pragma unroll
  for (int s = 0; s < SEQ; s++) { w[s] = __expf(acol[s] - m); Z += w[s]; }
  float inv = 1.f / Z;

  __hip_bfloat16* rowx1 = abf + (size_t)b * TWOD;             // [X1_9 | atty]
  __hip_bfloat16* rowx2 = abf + (size_t)(BATCH + b) * TWOD;   // [X2_9 | attx]
  for (int d = tid; d < DIM; d += 256) {
    float acc = 0.f;
#pragma unroll
    for (int s = 0; s < SEQ; s++) acc += w[s] * X1s[s * DIM + d];
    rowx2[DIM + d] = __float2bfloat16(acc * inv);   // attx
    rowx1[d] = __float2bfloat16(X1s[9 * DIM + d]);  // X1[b,9,:]
    rowx2[d] = __float2bfloat16(x29[d]);            // X2[b,9,:]
  }
}

// K2: cross-batch softmax stats per t
__global__ __launch_bounds__(256) void k_stats(const float* __restrict__ arow,
                                               float* __restrict__ stats) {
  int t = blockIdx.x;
  int tid = threadIdx.x, lane = tid & 63, wave = tid >> 6;
  __shared__ float wred[4];
  float m = -1e30f;
  for (int b = tid; b < BATCH; b += 256) m = fmaxf(m, arow[(size_t)b * 16 + t]);
  for (int off = 32; off; off >>= 1) m = fmaxf(m, __shfl_down(m, off, 64));
  if (lane == 0) wred[wave] = m;
  __syncthreads();
  m = fmaxf(fmaxf(wred[0], wred[1]), fmaxf(wred[2], wred[3]));
  __syncthreads();
  float z = 0.f;
  for (int b = tid; b < BATCH; b += 256) z += __expf(arow[(size_t)b * 16 + t] - m);
  for (int off = 32; off; off >>= 1) z += __shfl_down(z, off, 64);
  if (lane == 0) wred[wave] = z;
  __syncthreads();
  if (tid == 0) {
    stats[t] = m;
    stats[16 + t] = wred[0] + wred[1] + wred[2] + wred[3];
  }
}

// K3: atty[b,d] -> Abf[b][1024+d] (bf16)
__global__ __launch_bounds__(256) void k_atty(const float* __restrict__ X2,
                                              const float* __restrict__ arow,
                                              const float* __restrict__ stats,
                                              __hip_bfloat16* __restrict__ abf) {
  int b = blockIdx.x;
  int tid = threadIdx.x;
  __shared__ float wy[SEQ];
  if (tid < SEQ)
    wy[tid] = __expf(arow[(size_t)b * 16 + tid] - stats[tid]) / stats[16 + tid];
  __syncthreads();
  const float* x2b = X2 + (size_t)b * SEQ * DIM;
  __hip_bfloat16* dst = abf + (size_t)b * TWOD + DIM;
  for (int d = tid; d < DIM; d += 256) {
    float acc = 0.f;
#pragma unroll
    for (int t = 0; t < SEQ; t++) acc += wy[t] * x2b[t * DIM + d];
    dst[d] = __float2bfloat16(acc);
  }
}

// Transpose + f32->bf16: in R x C  ->  out C x R
__global__ __launch_bounds__(256) void k_transpose(const float* __restrict__ in,
                                                   __hip_bfloat16* __restrict__ out,
                                                   int R, int C) {
  __shared__ float t[32][33];
  int r0 = blockIdx.x * 32, c0 = blockIdx.y * 32;
  int tx = threadIdx.x & 31, ty = threadIdx.x >> 5;
#pragma unroll
  for (int i = 0; i < 4; i++)
    t[ty + 8 * i][tx] = in[(size_t)(r0 + ty + 8 * i) * C + c0 + tx];
  __syncthreads();
#pragma unroll
  for (int i = 0; i < 4; i++)
    out[(size_t)(c0 + ty + 8 * i) * R + r0 + tx] = __float2bfloat16(t[tx][ty + 8 * i]);
}

// MFMA GEMM: C[M,N] = A[M,K] @ Bt[N,K]^T + bias
// BM=BN=128, BK=32, 4 waves, each wave a 64x64 sub-tile (4x4 frags of 16x16x32).
// EPI=1: write bf16 with row-remap into ocb.  EPI=2: relu, write f32 h.
template <int EPI>
__global__ __launch_bounds__(256) void k_mfma_gemm(
    const __hip_bfloat16* __restrict__ A, const __hip_bfloat16* __restrict__ Bt,
    const float* __restrict__ bias, __hip_bfloat16* __restrict__ outb,
    float* __restrict__ outf, int K) {
  __shared__ short lds[8192];  // A tile: [0,4096) shorts, B tile: [4096,8192)
  int tid = threadIdx.x;
  int lane = tid & 63, wave = tid >> 6;
  int m0 = blockIdx.y * 128, n0 = blockIdx.x * 128;
  int wr = wave >> 1, wc = wave & 1;

  f32x4 acc[4][4] = {};

  int lrow = lane >> 2;  // row within 16-row chunk
  int ls = lane & 3;     // 16B slot within 64B row
  int g = lane >> 4, r16 = lane & 15;

  for (int k0 = 0; k0 < K; k0 += 32) {
#pragma unroll
    for (int c = 0; c < 2; c++) {
      int R0 = 16 * (2 * wave + c);
      int rr = R0 + lrow;
      int slot = ls ^ (rr & 3);  // inverse-swizzled global source (rule #21)
      const __hip_bfloat16* srcA = A + (size_t)(m0 + rr) * K + k0 + slot * 8;
      GLOAD_LDS16(srcA, &lds[R0 * 32]);
      const __hip_bfloat16* srcB = Bt + (size_t)(n0 + rr) * K + k0 + slot * 8;
      GLOAD_LDS16(srcB, &lds[4096 + R0 * 32]);
    }
    __syncthreads();

    bf16x8 af[4], bfr[4];
#pragma unroll
    for (int mi = 0; mi < 4; mi++) {
      int m = wr * 64 + mi * 16 + r16;
      af[mi] = *(const bf16x8*)&lds[m * 32 + ((g ^ (m & 3)) << 3)];
    }
#pragma unroll
    for (int ni = 0; ni < 4; ni++) {
      int n = wc * 64 + ni * 16 + r16;
      bfr[ni] = *(const bf16x8*)&lds[4096 + n * 32 + ((g ^ (n & 3)) << 3)];
    }
#pragma unroll
    for (int mi = 0; mi < 4; mi++)
#pragma unroll
      for (int ni = 0; ni < 4; ni++)
        acc[mi][ni] = __builtin_amdgcn_mfma_f32_16x16x32_bf16(
            af[mi], bfr[ni], acc[mi][ni], 0, 0, 0);
    __syncthreads();
  }

#pragma unroll
  for (int mi = 0; mi < 4; mi++) {
#pragma unroll
    for (int ni = 0; ni < 4; ni++) {
#pragma unroll
      for (int r = 0; r < 4; r++) {
        int m = m0 + wr * 64 + mi * 16 + g * 4 + r;
        int n = n0 + wc * 64 + ni * 16 + r16;
        float v = acc[mi][ni][r] + bias[n];
        if (EPI == 1) {
          int om = m & (BATCH - 1);
          int on = n + ((m >> 12) << 10);  // second half -> cols 1024..2047
          outb[(size_t)om * TWOD + on] = __float2bfloat16(v);
        } else {
          outf[(size_t)m * HID + n] = v > 0.f ? v : 0.f;
        }
      }
    }
  }
}

// K6: out[b] = sigmoid(dot(h[b,:], Wff) + bff)
__global__ __launch_bounds__(256) void k_final(const float* __restrict__ h,
                                               const float* __restrict__ Wff,
                                               const float* __restrict__ bff,
                                               float* __restrict__ out) {
  int b = blockIdx.x * 4 + (threadIdx.x >> 6);
  int lane = threadIdx.x & 63;
  const float* hb = h + (size_t)b * HID;
  float p = 0.f;
#pragma unroll
  for (int j = lane; j < HID; j += 64) p += hb[j] * Wff[j];
  for (int off = 32; off; off >>= 1) p += __shfl_down(p, off, 64);
  if (lane == 0) out[b] = 1.f / (1.f + __expf(-(p + bff[0])));
}

extern "C" void kernel_launch(void* const* d_in, const int* in_sizes, int n_in,
                              void* d_out, int out_size, void* d_ws, size_t ws_size,
                              hipStream_t stream) {
  const float* X1  = (const float*)d_in[0];
  const float* X2  = (const float*)d_in[1];
  const float* Wg  = (const float*)d_in[2];
  const float* bg  = (const float*)d_in[3];
  const float* Wfd = (const float*)d_in[4];
  const float* bfd = (const float*)d_in[5];
  const float* Wff = (const float*)d_in[6];
  const float* bff = (const float*)d_in[7];
  float* out = (float*)d_out;
  char* ws = (char*)d_ws;

  __hip_bfloat16* abf  = (__hip_bfloat16*)(ws + OFF_ABF);
  __hip_bfloat16* ocb  = (__hip_bfloat16*)(ws + OFF_OCB);
  __hip_bfloat16* wgt  = (__hip_bfloat16*)(ws + OFF_WGT);
  __hip_bfloat16* wfdt = (__hip_bfloat16*)(ws + OFF_WFDT);
  float* h     = (float*)(ws + OFF_H);
  float* arow  = (float*)(ws + OFF_AROW);
  float* stats = (float*)(ws + OFF_STATS);

  k_transpose<<<dim3(64, 32), 256, 0, stream>>>(Wg, wgt, TWOD, DIM);
  k_transpose<<<dim3(64, 16), 256, 0, stream>>>(Wfd, wfdt, TWOD, HID);
  k_attn1<<<BATCH, 256, 0, stream>>>(X1, X2, abf, arow);
  k_stats<<<SEQ, 256, 0, stream>>>(arow, stats);
  k_atty<<<BATCH, 256, 0, stream>>>(X2, arow, stats, abf);
  // GEMM1: M=8192, N=1024, K=2048 -> ocb (bf16, remapped)
  k_mfma_gemm<1><<<dim3(DIM / 128, 2 * BATCH / 128), 256, 0, stream>>>(
      abf, wgt, bg, ocb, nullptr, TWOD);
  // GEMM2: M=4096, N=512, K=2048 -> h = relu(. + bfd)
  k_mfma_gemm<2><<<dim3(HID / 128, BATCH / 128), 256, 0, stream>>>(
      ocb, wfdt, bfd, nullptr, h, TWOD);
  k_final<<<BATCH / 4, 256, 0, stream>>>(h, Wff, bff, out);
}

// Round 4
// 237.303 us; speedup vs baseline: 3.9847x; 1.4487x over previous
//
#include <hip/hip_runtime.h>
#include <hip/hip_bf16.h>

#define BATCH 4096
#define SEQ 10
#define DIM 1024
#define TWOD 2048
#define HID 512

typedef __attribute__((ext_vector_type(8))) short bf16x8;
typedef __attribute__((ext_vector_type(4))) float f32x4;

// ---------------- workspace layout (bytes) ----------------
#define OFF_ABF   0ull                 // bf16 [8192][2048]
#define OFF_OCB   (32ull << 20)        // bf16 [4096][2048]
#define OFF_WGT   (48ull << 20)        // bf16 [1024][2048]
#define OFF_WFDT  (52ull << 20)        // bf16 [512][2048]
#define OFF_H     (54ull << 20)        // f32  [4096][512]
#define OFF_AROW  (62ull << 20)        // f32  [4096*16]
#define OFF_STATS (OFF_AROW + 4096ull * 16 * 4)

#define GLOAD_LDS16(g, l)                                                     \
  __builtin_amdgcn_global_load_lds(                                           \
      (const __attribute__((address_space(1))) unsigned int*)(g),             \
      (__attribute__((address_space(3))) unsigned int*)(l), 16, 0, 0)

static __device__ inline void store_bf4(__hip_bfloat16* p, float4 v) {
  ushort4 u;
  __hip_bfloat16 a = __float2bfloat16(v.x), b = __float2bfloat16(v.y),
                 c = __float2bfloat16(v.z), d = __float2bfloat16(v.w);
  u.x = *(unsigned short*)&a; u.y = *(unsigned short*)&b;
  u.z = *(unsigned short*)&c; u.w = *(unsigned short*)&d;
  *(ushort4*)p = u;
}

// P1a: wave per batch. Hold X1[b] rows in regs; dots vs X2[b,9]; local softmax;
// apply attx from regs. Emit bf16: attx -> rowx2[1024+], X1_9 -> rowx1[0..],
// X2_9 -> rowx2[0..].
__global__ __launch_bounds__(256, 2) void k_scores_x(
    const float* __restrict__ X1, const float* __restrict__ X2,
    __hip_bfloat16* __restrict__ abf) {
  int b = blockIdx.x * 4 + (threadIdx.x >> 6);
  int lane = threadIdx.x & 63;
  const float* x1b = X1 + (size_t)b * SEQ * DIM;
  const float* x2b9 = X2 + (size_t)b * SEQ * DIM + 9 * DIM;

  float4 x29[4], r[SEQ][4];
#pragma unroll
  for (int i = 0; i < 4; i++)
    x29[i] = *(const float4*)(x2b9 + i * 256 + lane * 4);
#pragma unroll
  for (int s = 0; s < SEQ; s++)
#pragma unroll
    for (int i = 0; i < 4; i++)
      r[s][i] = *(const float4*)(x1b + s * DIM + i * 256 + lane * 4);

  float p[SEQ];
#pragma unroll
  for (int s = 0; s < SEQ; s++) {
    float4 acc4 = r[s][0] * x29[0] + r[s][1] * x29[1] + r[s][2] * x29[2] +
                  r[s][3] * x29[3];
    p[s] = acc4.x + acc4.y + acc4.z + acc4.w;
  }
#pragma unroll
  for (int off = 1; off < 64; off <<= 1)
#pragma unroll
    for (int s = 0; s < SEQ; s++) p[s] += __shfl_xor(p[s], off, 64);

  float m = -1e30f;
#pragma unroll
  for (int s = 0; s < SEQ; s++) m = fmaxf(m, p[s]);
  float w[SEQ], Z = 0.f;
#pragma unroll
  for (int s = 0; s < SEQ; s++) { w[s] = __expf(p[s] - m); Z += w[s]; }
  float inv = 1.f / Z;

  __hip_bfloat16* rowx1 = abf + (size_t)b * TWOD;            // [X1_9 | atty]
  __hip_bfloat16* rowx2 = abf + (size_t)(BATCH + b) * TWOD;  // [X2_9 | attx]
#pragma unroll
  for (int i = 0; i < 4; i++) {
    int d = i * 256 + lane * 4;
    float4 ax = r[0][i] * w[0];
#pragma unroll
    for (int s = 1; s < SEQ; s++) ax += r[s][i] * w[s];
    ax *= inv;
    store_bf4(rowx2 + DIM + d, ax);       // attx
    store_bf4(rowx1 + d, r[9][i]);        // X1[b,9,:]
    store_bf4(rowx2 + d, x29[i]);         // X2[b,9,:]
  }
}

// P1b: wave per batch. Stream X2 rows; dots vs X1[b,9]; write raw arow.
__global__ __launch_bounds__(256) void k_scores_y(const float* __restrict__ X1,
                                                  const float* __restrict__ X2,
                                                  float* __restrict__ arow) {
  int b = blockIdx.x * 4 + (threadIdx.x >> 6);
  int lane = threadIdx.x & 63;
  const float* x1b9 = X1 + (size_t)b * SEQ * DIM + 9 * DIM;
  const float* x2b = X2 + (size_t)b * SEQ * DIM;

  float4 x19[4];
#pragma unroll
  for (int i = 0; i < 4; i++)
    x19[i] = *(const float4*)(x1b9 + i * 256 + lane * 4);

  float p[SEQ];
#pragma unroll
  for (int t = 0; t < SEQ; t++) {
    float4 acc4 = {0.f, 0.f, 0.f, 0.f};
#pragma unroll
    for (int i = 0; i < 4; i++) {
      float4 rt = *(const float4*)(x2b + t * DIM + i * 256 + lane * 4);
      acc4 += rt * x19[i];
    }
    p[t] = acc4.x + acc4.y + acc4.z + acc4.w;
  }
#pragma unroll
  for (int off = 1; off < 64; off <<= 1)
#pragma unroll
    for (int t = 0; t < SEQ; t++) p[t] += __shfl_xor(p[t], off, 64);

#pragma unroll
  for (int t = 0; t < SEQ; t++)
    if (lane == t) arow[(size_t)b * 16 + t] = p[t];
}

// P2: cross-batch softmax stats per t
__global__ __launch_bounds__(256) void k_stats(const float* __restrict__ arow,
                                               float* __restrict__ stats) {
  int t = blockIdx.x;
  int tid = threadIdx.x, lane = tid & 63, wave = tid >> 6;
  __shared__ float wred[4];
  float m = -1e30f;
  for (int b = tid; b < BATCH; b += 256) m = fmaxf(m, arow[(size_t)b * 16 + t]);
  for (int off = 32; off; off >>= 1) m = fmaxf(m, __shfl_down(m, off, 64));
  if (lane == 0) wred[wave] = m;
  __syncthreads();
  m = fmaxf(fmaxf(wred[0], wred[1]), fmaxf(wred[2], wred[3]));
  __syncthreads();
  float z = 0.f;
  for (int b = tid; b < BATCH; b += 256) z += __expf(arow[(size_t)b * 16 + t] - m);
  for (int off = 32; off; off >>= 1) z += __shfl_down(z, off, 64);
  if (lane == 0) wred[wave] = z;
  __syncthreads();
  if (tid == 0) {
    stats[t] = m;
    stats[16 + t] = wred[0] + wred[1] + wred[2] + wred[3];
  }
}

// P3: atty[b,d] = sum_t wy[b,t] X2[b,t,d] -> rowx1[1024+d] (bf16). Streaming.
__global__ __launch_bounds__(256) void k_apply_y(const float* __restrict__ X2,
                                                 const float* __restrict__ arow,
                                                 const float* __restrict__ stats,
                                                 __hip_bfloat16* __restrict__ abf) {
  int b = blockIdx.x;
  int wave = threadIdx.x >> 6, lane = threadIdx.x & 63;
  float wy[SEQ];
#pragma unroll
  for (int t = 0; t < SEQ; t++)
    wy[t] = __expf(arow[(size_t)b * 16 + t] - stats[t]) / stats[16 + t];
  const float* x2b = X2 + (size_t)b * SEQ * DIM;
  int d = wave * 256 + lane * 4;
  float4 acc = {0.f, 0.f, 0.f, 0.f};
#pragma unroll
  for (int t = 0; t < SEQ; t++)
    acc += wy[t] * *(const float4*)(x2b + t * DIM + d);
  store_bf4(abf + (size_t)b * TWOD + DIM + d, acc);
}

// Transpose + f32->bf16: in R x C  ->  out C x R
__global__ __launch_bounds__(256) void k_transpose(const float* __restrict__ in,
                                                   __hip_bfloat16* __restrict__ out,
                                                   int R, int C) {
  __shared__ float t[32][33];
  int r0 = blockIdx.x * 32, c0 = blockIdx.y * 32;
  int tx = threadIdx.x & 31, ty = threadIdx.x >> 5;
#pragma unroll
  for (int i = 0; i < 4; i++)
    t[ty + 8 * i][tx] = in[(size_t)(r0 + ty + 8 * i) * C + c0 + tx];
  __syncthreads();
#pragma unroll
  for (int i = 0; i < 4; i++)
    out[(size_t)(c0 + ty + 8 * i) * R + r0 + tx] = __float2bfloat16(t[tx][ty + 8 * i]);
}

// MFMA GEMM: C[M,N] = A[M,K] @ Bt[N,K]^T + bias
template <int EPI>
__global__ __launch_bounds__(256) void k_mfma_gemm(
    const __hip_bfloat16* __restrict__ A, const __hip_bfloat16* __restrict__ Bt,
    const float* __restrict__ bias, __hip_bfloat16* __restrict__ outb,
    float* __restrict__ outf, int K) {
  __shared__ short lds[8192];  // A tile: [0,4096) shorts, B tile: [4096,8192)
  int tid = threadIdx.x;
  int lane = tid & 63, wave = tid >> 6;
  int m0 = blockIdx.y * 128, n0 = blockIdx.x * 128;
  int wr = wave >> 1, wc = wave & 1;

  f32x4 acc[4][4] = {};

  int lrow = lane >> 2;
  int ls = lane & 3;
  int g = lane >> 4, r16 = lane & 15;

  for (int k0 = 0; k0 < K; k0 += 32) {
#pragma unroll
    for (int c = 0; c < 2; c++) {
      int R0 = 16 * (2 * wave + c);
      int rr = R0 + lrow;
      int slot = ls ^ (rr & 3);
      const __hip_bfloat16* srcA = A + (size_t)(m0 + rr) * K + k0 + slot * 8;
      GLOAD_LDS16(srcA, &lds[R0 * 32]);
      const __hip_bfloat16* srcB = Bt + (size_t)(n0 + rr) * K + k0 + slot * 8;
      GLOAD_LDS16(srcB, &lds[4096 + R0 * 32]);
    }
    __syncthreads();

    bf16x8 af[4], bfr[4];
#pragma unroll
    for (int mi = 0; mi < 4; mi++) {
      int m = wr * 64 + mi * 16 + r16;
      af[mi] = *(const bf16x8*)&lds[m * 32 + ((g ^ (m & 3)) << 3)];
    }
#pragma unroll
    for (int ni = 0; ni < 4; ni++) {
      int n = wc * 64 + ni * 16 + r16;
      bfr[ni] = *(const bf16x8*)&lds[4096 + n * 32 + ((g ^ (n & 3)) << 3)];
    }
#pragma unroll
    for (int mi = 0; mi < 4; mi++)
#pragma unroll
      for (int ni = 0; ni < 4; ni++)
        acc[mi][ni] = __builtin_amdgcn_mfma_f32_16x16x32_bf16(
            af[mi], bfr[ni], acc[mi][ni], 0, 0, 0);
    __syncthreads();
  }

#pragma unroll
  for (int mi = 0; mi < 4; mi++) {
#pragma unroll
    for (int ni = 0; ni < 4; ni++) {
#pragma unroll
      for (int r = 0; r < 4; r++) {
        int m = m0 + wr * 64 + mi * 16 + g * 4 + r;
        int n = n0 + wc * 64 + ni * 16 + r16;
        float v = acc[mi][ni][r] + bias[n];
        if (EPI == 1) {
          int om = m & (BATCH - 1);
          int on = n + ((m >> 12) << 10);
          outb[(size_t)om * TWOD + on] = __float2bfloat16(v);
        } else {
          outf[(size_t)m * HID + n] = v > 0.f ? v : 0.f;
        }
      }
    }
  }
}

// K6: out[b] = sigmoid(dot(h[b,:], Wff) + bff)
__global__ __launch_bounds__(256) void k_final(const float* __restrict__ h,
                                               const float* __restrict__ Wff,
                                               const float* __restrict__ bff,
                                               float* __restrict__ out) {
  int b = blockIdx.x * 4 + (threadIdx.x >> 6);
  int lane = threadIdx.x & 63;
  const float* hb = h + (size_t)b * HID;
  float p = 0.f;
#pragma unroll
  for (int j = lane; j < HID; j += 64) p += hb[j] * Wff[j];
  for (int off = 32; off; off >>= 1) p += __shfl_down(p, off, 64);
  if (lane == 0) out[b] = 1.f / (1.f + __expf(-(p + bff[0])));
}

extern "C" void kernel_launch(void* const* d_in, const int* in_sizes, int n_in,
                              void* d_out, int out_size, void* d_ws, size_t ws_size,
                              hipStream_t stream) {
  const float* X1  = (const float*)d_in[0];
  const float* X2  = (const float*)d_in[1];
  const float* Wg  = (const float*)d_in[2];
  const float* bg  = (const float*)d_in[3];
  const float* Wfd = (const float*)d_in[4];
  const float* bfd = (const float*)d_in[5];
  const float* Wff = (const float*)d_in[6];
  const float* bff = (const float*)d_in[7];
  float* out = (float*)d_out;
  char* ws = (char*)d_ws;

  __hip_bfloat16* abf  = (__hip_bfloat16*)(ws + OFF_ABF);
  __hip_bfloat16* ocb  = (__hip_bfloat16*)(ws + OFF_OCB);
  __hip_bfloat16* wgt  = (__hip_bfloat16*)(ws + OFF_WGT);
  __hip_bfloat16* wfdt = (__hip_bfloat16*)(ws + OFF_WFDT);
  float* h     = (float*)(ws + OFF_H);
  float* arow  = (float*)(ws + OFF_AROW);
  float* stats = (float*)(ws + OFF_STATS);

  k_transpose<<<dim3(64, 32), 256, 0, stream>>>(Wg, wgt, TWOD, DIM);
  k_transpose<<<dim3(64, 16), 256, 0, stream>>>(Wfd, wfdt, TWOD, HID);
  k_scores_y<<<BATCH / 4, 256, 0, stream>>>(X1, X2, arow);
  k_scores_x<<<BATCH / 4, 256, 0, stream>>>(X1, X2, abf);
  k_stats<<<SEQ, 256, 0, stream>>>(arow, stats);
  k_apply_y<<<BATCH, 256, 0, stream>>>(X2, arow, stats, abf);
  // GEMM1: M=8192, N=1024, K=2048 -> ocb (bf16, remapped)
  k_mfma_gemm<1><<<dim3(DIM / 128, 2 * BATCH / 128), 256, 0, stream>>>(
      abf, wgt, bg, ocb, nullptr, TWOD);
  // GEMM2: M=4096, N=512, K=2048 -> h = relu(. + bfd)
  k_mfma_gemm<2><<<dim3(HID / 128, BATCH / 128), 256, 0, stream>>>(
      ocb, wfdt, bfd, nullptr, h, TWOD);
  k_final<<<BATCH / 4, 256, 0, stream>>>(h, Wff, bff, out);
}

// Round 5
// 223.638 us; speedup vs baseline: 4.2282x; 1.0611x over previous
//
#include <hip/hip_runtime.h>
#include <hip/hip_bf16.h>

#define BATCH 4096
#define SEQ 10
#define DIM 1024
#define TWOD 2048
#define HID 512

typedef __attribute__((ext_vector_type(8))) short bf16x8;
typedef __attribute__((ext_vector_type(4))) float f32x4;

// ---------------- workspace layout (bytes) ----------------
#define OFF_ABF   0ull                 // bf16 [8192][2048]
#define OFF_OCB   (32ull << 20)        // bf16 [4096][2048]
#define OFF_WGT   (48ull << 20)        // bf16 [1024][2048]
#define OFF_WFDT  (52ull << 20)        // bf16 [512][2048]
#define OFF_H     (54ull << 20)        // f32  [4096][512]
#define OFF_AROW  (62ull << 20)        // f32  [4096*16]
#define OFF_STATS (OFF_AROW + 4096ull * 16 * 4)

#define GLOAD_LDS16(g, l)                                                     \
  __builtin_amdgcn_global_load_lds(                                           \
      (const __attribute__((address_space(1))) unsigned int*)(g),             \
      (__attribute__((address_space(3))) unsigned int*)(l), 16, 0, 0)

// XOR-swizzle over the 4 16B k-slots of a 64B LDS row. sw(r)=(r+(r>>2))&3
// makes bank-quad (4r+pos) mod 8 uniform over 16-row frag reads (2-way, free)
// vs (r&3) which was 4-way.
#define SW(r) (((r) + ((r) >> 2)) & 3)

static __device__ inline void store_bf4(__hip_bfloat16* p, float4 v) {
  ushort4 u;
  __hip_bfloat16 a = __float2bfloat16(v.x), b = __float2bfloat16(v.y),
                 c = __float2bfloat16(v.z), d = __float2bfloat16(v.w);
  u.x = *(unsigned short*)&a; u.y = *(unsigned short*)&b;
  u.z = *(unsigned short*)&c; u.w = *(unsigned short*)&d;
  *(ushort4*)p = u;
}

// P1a: wave per batch. Hold X1[b] rows in regs; dots vs X2[b,9]; local softmax;
// apply attx from regs. Emits attx -> rowx2[1024+], X1_9 -> rowx1, X2_9 -> rowx2.
__global__ __launch_bounds__(256, 2) void k_scores_x(
    const float* __restrict__ X1, const float* __restrict__ X2,
    __hip_bfloat16* __restrict__ abf) {
  int b = blockIdx.x * 4 + (threadIdx.x >> 6);
  int lane = threadIdx.x & 63;
  const float* x1b = X1 + (size_t)b * SEQ * DIM;
  const float* x2b9 = X2 + (size_t)b * SEQ * DIM + 9 * DIM;

  float4 x29[4], r[SEQ][4];
#pragma unroll
  for (int i = 0; i < 4; i++)
    x29[i] = *(const float4*)(x2b9 + i * 256 + lane * 4);
#pragma unroll
  for (int s = 0; s < SEQ; s++)
#pragma unroll
    for (int i = 0; i < 4; i++)
      r[s][i] = *(const float4*)(x1b + s * DIM + i * 256 + lane * 4);

  float p[SEQ];
#pragma unroll
  for (int s = 0; s < SEQ; s++) {
    float4 acc4 = r[s][0] * x29[0] + r[s][1] * x29[1] + r[s][2] * x29[2] +
                  r[s][3] * x29[3];
    p[s] = acc4.x + acc4.y + acc4.z + acc4.w;
  }
#pragma unroll
  for (int off = 1; off < 64; off <<= 1)
#pragma unroll
    for (int s = 0; s < SEQ; s++) p[s] += __shfl_xor(p[s], off, 64);

  float m = -1e30f;
#pragma unroll
  for (int s = 0; s < SEQ; s++) m = fmaxf(m, p[s]);
  float w[SEQ], Z = 0.f;
#pragma unroll
  for (int s = 0; s < SEQ; s++) { w[s] = __expf(p[s] - m); Z += w[s]; }
  float inv = 1.f / Z;

  __hip_bfloat16* rowx1 = abf + (size_t)b * TWOD;            // [X1_9 | atty]
  __hip_bfloat16* rowx2 = abf + (size_t)(BATCH + b) * TWOD;  // [X2_9 | attx]
#pragma unroll
  for (int i = 0; i < 4; i++) {
    int d = i * 256 + lane * 4;
    float4 ax = r[0][i] * w[0];
#pragma unroll
    for (int s = 1; s < SEQ; s++) ax += r[s][i] * w[s];
    ax *= inv;
    store_bf4(rowx2 + DIM + d, ax);       // attx
    store_bf4(rowx1 + d, r[9][i]);        // X1[b,9,:]
    store_bf4(rowx2 + d, x29[i]);         // X2[b,9,:]
  }
}

// P1b: wave per batch. Stream X2 rows; dots vs X1[b,9]; write raw arow.
__global__ __launch_bounds__(256) void k_scores_y(const float* __restrict__ X1,
                                                  const float* __restrict__ X2,
                                                  float* __restrict__ arow) {
  int b = blockIdx.x * 4 + (threadIdx.x >> 6);
  int lane = threadIdx.x & 63;
  const float* x1b9 = X1 + (size_t)b * SEQ * DIM + 9 * DIM;
  const float* x2b = X2 + (size_t)b * SEQ * DIM;

  float4 x19[4];
#pragma unroll
  for (int i = 0; i < 4; i++)
    x19[i] = *(const float4*)(x1b9 + i * 256 + lane * 4);

  float p[SEQ];
#pragma unroll
  for (int t = 0; t < SEQ; t++) {
    float4 acc4 = {0.f, 0.f, 0.f, 0.f};
#pragma unroll
    for (int i = 0; i < 4; i++) {
      float4 rt = *(const float4*)(x2b + t * DIM + i * 256 + lane * 4);
      acc4 += rt * x19[i];
    }
    p[t] = acc4.x + acc4.y + acc4.z + acc4.w;
  }
#pragma unroll
  for (int off = 1; off < 64; off <<= 1)
#pragma unroll
    for (int t = 0; t < SEQ; t++) p[t] += __shfl_xor(p[t], off, 64);

#pragma unroll
  for (int t = 0; t < SEQ; t++)
    if (lane == t) arow[(size_t)b * 16 + t] = p[t];
}

// P2: cross-batch softmax stats per t
__global__ __launch_bounds__(256) void k_stats(const float* __restrict__ arow,
                                               float* __restrict__ stats) {
  int t = blockIdx.x;
  int tid = threadIdx.x, lane = tid & 63, wave = tid >> 6;
  __shared__ float wred[4];
  float m = -1e30f;
  for (int b = tid; b < BATCH; b += 256) m = fmaxf(m, arow[(size_t)b * 16 + t]);
  for (int off = 32; off; off >>= 1) m = fmaxf(m, __shfl_down(m, off, 64));
  if (lane == 0) wred[wave] = m;
  __syncthreads();
  m = fmaxf(fmaxf(wred[0], wred[1]), fmaxf(wred[2], wred[3]));
  __syncthreads();
  float z = 0.f;
  for (int b = tid; b < BATCH; b += 256) z += __expf(arow[(size_t)b * 16 + t] - m);
  for (int off = 32; off; off >>= 1) z += __shfl_down(z, off, 64);
  if (lane == 0) wred[wave] = z;
  __syncthreads();
  if (tid == 0) {
    stats[t] = m;
    stats[16 + t] = wred[0] + wred[1] + wred[2] + wred[3];
  }
}

// P3: atty[b,d] = sum_t wy[b,t] X2[b,t,d] -> rowx1[1024+d] (bf16). Streaming;
// scheduled right after k_scores_y so X2 is L3-warm.
__global__ __launch_bounds__(256) void k_apply_y(const float* __restrict__ X2,
                                                 const float* __restrict__ arow,
                                                 const float* __restrict__ stats,
                                                 __hip_bfloat16* __restrict__ abf) {
  int b = blockIdx.x;
  int wave = threadIdx.x >> 6, lane = threadIdx.x & 63;
  float wy[SEQ];
#pragma unroll
  for (int t = 0; t < SEQ; t++)
    wy[t] = __expf(arow[(size_t)b * 16 + t] - stats[t]) / stats[16 + t];
  const float* x2b = X2 + (size_t)b * SEQ * DIM;
  int d = wave * 256 + lane * 4;
  float4 acc = {0.f, 0.f, 0.f, 0.f};
#pragma unroll
  for (int t = 0; t < SEQ; t++)
    acc += wy[t] * *(const float4*)(x2b + t * DIM + d);
  store_bf4(abf + (size_t)b * TWOD + DIM + d, acc);
}

// Transpose + f32->bf16: in R x C  ->  out C x R
__global__ __launch_bounds__(256) void k_transpose(const float* __restrict__ in,
                                                   __hip_bfloat16* __restrict__ out,
                                                   int R, int C) {
  __shared__ float t[32][33];
  int r0 = blockIdx.x * 32, c0 = blockIdx.y * 32;
  int tx = threadIdx.x & 31, ty = threadIdx.x >> 5;
#pragma unroll
  for (int i = 0; i < 4; i++)
    t[ty + 8 * i][tx] = in[(size_t)(r0 + ty + 8 * i) * C + c0 + tx];
  __syncthreads();
#pragma unroll
  for (int i = 0; i < 4; i++)
    out[(size_t)(c0 + ty + 8 * i) * R + r0 + tx] = __float2bfloat16(t[tx][ty + 8 * i]);
}

// MFMA GEMM: C[M,N] = A[M,K] @ Bt[N,K]^T + bias
// BM=128, BN in {128,64}, BK=32, 4 waves. Wave tile: 64 x BN/2.
// EPI=1: write bf16 with row-remap into ocb.  EPI=2: relu, write f32 h.
template <int BN, int EPI>
__global__ __launch_bounds__(256) void k_mfma_gemm(
    const __hip_bfloat16* __restrict__ A, const __hip_bfloat16* __restrict__ Bt,
    const float* __restrict__ bias, __hip_bfloat16* __restrict__ outb,
    float* __restrict__ outf, int K) {
  constexpr int NI = BN / 32;  // n-frags per wave
  __shared__ short lds[4096 + BN * 32];  // A: [0,4096), B: [4096, ...)
  int tid = threadIdx.x;
  int lane = tid & 63, wave = tid >> 6;
  int m0 = blockIdx.y * 128, n0 = blockIdx.x * BN;
  int wr = wave >> 1, wc = wave & 1;

  f32x4 acc[4][NI] = {};

  int lrow = lane >> 2;
  int ls = lane & 3;
  int g = lane >> 4, r16 = lane & 15;

  for (int k0 = 0; k0 < K; k0 += 32) {
#pragma unroll
    for (int c = 0; c < 2; c++) {
      int R0 = 16 * (2 * wave + c);
      int rr = R0 + lrow;
      int slot = ls ^ SW(rr);
      const __hip_bfloat16* srcA = A + (size_t)(m0 + rr) * K + k0 + slot * 8;
      GLOAD_LDS16(srcA, &lds[R0 * 32]);
      if (BN == 128 || c == 0) {
        int RB = (BN == 128) ? R0 : 16 * wave;
        int rb = RB + lrow;
        int slotb = ls ^ SW(rb);
        const __hip_bfloat16* srcB = Bt + (size_t)(n0 + rb) * K + k0 + slotb * 8;
        GLOAD_LDS16(srcB, &lds[4096 + RB * 32]);
      }
    }
    __syncthreads();

    bf16x8 af[4], bfr[NI];
#pragma unroll
    for (int mi = 0; mi < 4; mi++) {
      int m = wr * 64 + mi * 16 + r16;
      af[mi] = *(const bf16x8*)&lds[m * 32 + ((g ^ SW(m)) << 3)];
    }
#pragma unroll
    for (int ni = 0; ni < NI; ni++) {
      int n = wc * (BN / 2) + ni * 16 + r16;
      bfr[ni] = *(const bf16x8*)&lds[4096 + n * 32 + ((g ^ SW(n)) << 3)];
    }
#pragma unroll
    for (int mi = 0; mi < 4; mi++)
#pragma unroll
      for (int ni = 0; ni < NI; ni++)
        acc[mi][ni] = __builtin_amdgcn_mfma_f32_16x16x32_bf16(
            af[mi], bfr[ni], acc[mi][ni], 0, 0, 0);
    __syncthreads();
  }

#pragma unroll
  for (int mi = 0; mi < 4; mi++) {
#pragma unroll
    for (int ni = 0; ni < NI; ni++) {
#pragma unroll
      for (int r = 0; r < 4; r++) {
        int m = m0 + wr * 64 + mi * 16 + g * 4 + r;
        int n = n0 + wc * (BN / 2) + ni * 16 + r16;
        float v = acc[mi][ni][r] + bias[n];
        if (EPI == 1) {
          int om = m & (BATCH - 1);
          int on = n + ((m >> 12) << 10);
          outb[(size_t)om * TWOD + on] = __float2bfloat16(v);
        } else {
          outf[(size_t)m * HID + n] = v > 0.f ? v : 0.f;
        }
      }
    }
  }
}

// K6: out[b] = sigmoid(dot(h[b,:], Wff) + bff)
__global__ __launch_bounds__(256) void k_final(const float* __restrict__ h,
                                               const float* __restrict__ Wff,
                                               const float* __restrict__ bff,
                                               float* __restrict__ out) {
  int b = blockIdx.x * 4 + (threadIdx.x >> 6);
  int lane = threadIdx.x & 63;
  const float* hb = h + (size_t)b * HID;
  float p = 0.f;
#pragma unroll
  for (int j = lane; j < HID; j += 64) p += hb[j] * Wff[j];
  for (int off = 32; off; off >>= 1) p += __shfl_down(p, off, 64);
  if (lane == 0) out[b] = 1.f / (1.f + __expf(-(p + bff[0])));
}

extern "C" void kernel_launch(void* const* d_in, const int* in_sizes, int n_in,
                              void* d_out, int out_size, void* d_ws, size_t ws_size,
                              hipStream_t stream) {
  const float* X1  = (const float*)d_in[0];
  const float* X2  = (const float*)d_in[1];
  const float* Wg  = (const float*)d_in[2];
  const float* bg  = (const float*)d_in[3];
  const float* Wfd = (const float*)d_in[4];
  const float* bfd = (const float*)d_in[5];
  const float* Wff = (const float*)d_in[6];
  const float* bff = (const float*)d_in[7];
  float* out = (float*)d_out;
  char* ws = (char*)d_ws;

  __hip_bfloat16* abf  = (__hip_bfloat16*)(ws + OFF_ABF);
  __hip_bfloat16* ocb  = (__hip_bfloat16*)(ws + OFF_OCB);
  __hip_bfloat16* wgt  = (__hip_bfloat16*)(ws + OFF_WGT);
  __hip_bfloat16* wfdt = (__hip_bfloat16*)(ws + OFF_WFDT);
  float* h     = (float*)(ws + OFF_H);
  float* arow  = (float*)(ws + OFF_AROW);
  float* stats = (float*)(ws + OFF_STATS);

  k_transpose<<<dim3(64, 32), 256, 0, stream>>>(Wg, wgt, TWOD, DIM);
  k_transpose<<<dim3(64, 16), 256, 0, stream>>>(Wfd, wfdt, TWOD, HID);
  // X1 pass first, then X2 pass, so apply_y's X2 re-read is L3-warm.
  k_scores_x<<<BATCH / 4, 256, 0, stream>>>(X1, X2, abf);
  k_scores_y<<<BATCH / 4, 256, 0, stream>>>(X1, X2, arow);
  k_stats<<<SEQ, 256, 0, stream>>>(arow, stats);
  k_apply_y<<<BATCH, 256, 0, stream>>>(X2, arow, stats, abf);
  // GEMM1: M=8192, N=1024, K=2048 -> ocb (bf16, remapped)
  k_mfma_gemm<128, 1><<<dim3(DIM / 128, 2 * BATCH / 128), 256, 0, stream>>>(
      abf, wgt, bg, ocb, nullptr, TWOD);
  // GEMM2: M=4096, N=512, K=2048 -> h = relu(. + bfd); BN=64 -> 256 blocks
  k_mfma_gemm<64, 2><<<dim3(HID / 64, BATCH / 128), 256, 0, stream>>>(
      ocb, wfdt, bfd, nullptr, h, TWOD);
  k_final<<<BATCH / 4, 256, 0, stream>>>(h, Wff, bff, out);
}

// Round 6
// 207.986 us; speedup vs baseline: 4.5464x; 1.0753x over previous
//
#include <hip/hip_runtime.h>
#include <hip/hip_bf16.h>

#define BATCH 4096
#define SEQ 10
#define DIM 1024
#define TWOD 2048
#define HID 512

typedef __attribute__((ext_vector_type(8))) short bf16x8;
typedef __attribute__((ext_vector_type(4))) float f32x4;

// ---------------- workspace layout (bytes) ----------------
#define OFF_ABF   0ull                 // bf16 [8192][2048]
#define OFF_OCB   (32ull << 20)        // bf16 [4096][2048]
#define OFF_WGT   (48ull << 20)        // bf16 [1024][2048]
#define OFF_WFDT  (52ull << 20)        // bf16 [512][2048]
#define OFF_LOG   (54ull << 20)        // f32  [4096] logit accumulator
#define OFF_AROW  (62ull << 20)        // f32  [4096*16]
#define OFF_STATS (OFF_AROW + 4096ull * 16 * 4)

#define GLOAD_LDS16(g, l)                                                     \
  __builtin_amdgcn_global_load_lds(                                           \
      (const __attribute__((address_space(1))) unsigned int*)(g),             \
      (__attribute__((address_space(3))) unsigned int*)(l), 16, 0, 0)

// XOR-swizzle over the 4 16B k-slots of a 64B LDS row. sw(r)=(r+(r>>2))&3
// makes the bank-quad pattern uniform over 16-row frag reads (2-way, free).
#define SW(r) (((r) + ((r) >> 2)) & 3)

static __device__ inline void store_bf4(__hip_bfloat16* p, float4 v) {
  ushort4 u;
  __hip_bfloat16 a = __float2bfloat16(v.x), b = __float2bfloat16(v.y),
                 c = __float2bfloat16(v.z), d = __float2bfloat16(v.w);
  u.x = *(unsigned short*)&a; u.y = *(unsigned short*)&b;
  u.z = *(unsigned short*)&c; u.w = *(unsigned short*)&d;
  *(ushort4*)p = u;
}

// P1: wave per batch. X1[b] rows held in regs; X2[b] streamed once.
// Produces: arow (raw y-scores), attx (bf16), X1_9/X2_9 bf16 copies.
// Also zeroes logits[b] for the fused GEMM2 accumulator.
__global__ __launch_bounds__(256, 2) void k_scores(
    const float* __restrict__ X1, const float* __restrict__ X2,
    __hip_bfloat16* __restrict__ abf, float* __restrict__ arow,
    float* __restrict__ logits) {
  int b = blockIdx.x * 4 + (threadIdx.x >> 6);
  int lane = threadIdx.x & 63;
  if (lane == 0) logits[b] = 0.f;
  const float* x1b = X1 + (size_t)b * SEQ * DIM;
  const float* x2b = X2 + (size_t)b * SEQ * DIM;
  __hip_bfloat16* rowx1 = abf + (size_t)b * TWOD;            // [X1_9 | atty]
  __hip_bfloat16* rowx2 = abf + (size_t)(BATCH + b) * TWOD;  // [X2_9 | attx]

  float4 r[SEQ][4];
#pragma unroll
  for (int s = 0; s < SEQ; s++)
#pragma unroll
    for (int i = 0; i < 4; i++)
      r[s][i] = *(const float4*)(x1b + s * DIM + i * 256 + lane * 4);

  float py[SEQ], px[SEQ];
#pragma unroll
  for (int t = 0; t < SEQ; t++) {
    float4 x2r[4];
#pragma unroll
    for (int i = 0; i < 4; i++)
      x2r[i] = *(const float4*)(x2b + t * DIM + i * 256 + lane * 4);
    float4 a4 = r[9][0] * x2r[0] + r[9][1] * x2r[1] + r[9][2] * x2r[2] +
                r[9][3] * x2r[3];
    py[t] = a4.x + a4.y + a4.z + a4.w;
    if (t == 9) {
#pragma unroll
      for (int s = 0; s < SEQ; s++) {
        float4 b4 = r[s][0] * x2r[0] + r[s][1] * x2r[1] + r[s][2] * x2r[2] +
                    r[s][3] * x2r[3];
        px[s] = b4.x + b4.y + b4.z + b4.w;
      }
#pragma unroll
      for (int i = 0; i < 4; i++)  // X2[b,9,:] bf16 copy
        store_bf4(rowx2 + i * 256 + lane * 4, x2r[i]);
    }
  }
#pragma unroll
  for (int off = 1; off < 64; off <<= 1) {
#pragma unroll
    for (int t = 0; t < SEQ; t++) py[t] += __shfl_xor(py[t], off, 64);
#pragma unroll
    for (int s = 0; s < SEQ; s++) px[s] += __shfl_xor(px[s], off, 64);
  }

#pragma unroll
  for (int t = 0; t < SEQ; t++)
    if (lane == t) arow[(size_t)b * 16 + t] = py[t];

  float m = -1e30f;
#pragma unroll
  for (int s = 0; s < SEQ; s++) m = fmaxf(m, px[s]);
  float w[SEQ], Z = 0.f;
#pragma unroll
  for (int s = 0; s < SEQ; s++) { w[s] = __expf(px[s] - m); Z += w[s]; }
  float inv = 1.f / Z;

#pragma unroll
  for (int i = 0; i < 4; i++) {
    int d = i * 256 + lane * 4;
    float4 ax = r[0][i] * w[0];
#pragma unroll
    for (int s = 1; s < SEQ; s++) ax += r[s][i] * w[s];
    ax *= inv;
    store_bf4(rowx2 + DIM + d, ax);   // attx
    store_bf4(rowx1 + d, r[9][i]);    // X1[b,9,:]
  }
}

// P2: cross-batch softmax stats per t
__global__ __launch_bounds__(256) void k_stats(const float* __restrict__ arow,
                                               float* __restrict__ stats) {
  int t = blockIdx.x;
  int tid = threadIdx.x, lane = tid & 63, wave = tid >> 6;
  __shared__ float wred[4];
  float m = -1e30f;
  for (int b = tid; b < BATCH; b += 256) m = fmaxf(m, arow[(size_t)b * 16 + t]);
  for (int off = 32; off; off >>= 1) m = fmaxf(m, __shfl_down(m, off, 64));
  if (lane == 0) wred[wave] = m;
  __syncthreads();
  m = fmaxf(fmaxf(wred[0], wred[1]), fmaxf(wred[2], wred[3]));
  __syncthreads();
  float z = 0.f;
  for (int b = tid; b < BATCH; b += 256) z += __expf(arow[(size_t)b * 16 + t] - m);
  for (int off = 32; off; off >>= 1) z += __shfl_down(z, off, 64);
  if (lane == 0) wred[wave] = z;
  __syncthreads();
  if (tid == 0) {
    stats[t] = m;
    stats[16 + t] = wred[0] + wred[1] + wred[2] + wred[3];
  }
}

// P3: atty[b,d] = sum_t wy[b,t] X2[b,t,d] -> rowx1[1024+d] (bf16). L3-warm X2.
__global__ __launch_bounds__(256) void k_apply_y(const float* __restrict__ X2,
                                                 const float* __restrict__ arow,
                                                 const float* __restrict__ stats,
                                                 __hip_bfloat16* __restrict__ abf) {
  int b = blockIdx.x;
  int wave = threadIdx.x >> 6, lane = threadIdx.x & 63;
  float wy[SEQ];
#pragma unroll
  for (int t = 0; t < SEQ; t++)
    wy[t] = __expf(arow[(size_t)b * 16 + t] - stats[t]) / stats[16 + t];
  const float* x2b = X2 + (size_t)b * SEQ * DIM;
  int d = wave * 256 + lane * 4;
  float4 acc = {0.f, 0.f, 0.f, 0.f};
#pragma unroll
  for (int t = 0; t < SEQ; t++)
    acc += wy[t] * *(const float4*)(x2b + t * DIM + d);
  store_bf4(abf + (size_t)b * TWOD + DIM + d, acc);
}

// Both weight transposes in one launch. Wg: 2048x1024 -> wgt 1024x2048 (bf16);
// Wfd: 2048x512 -> wfdt 512x2048 (bf16).
__global__ __launch_bounds__(256) void k_transpose_both(
    const float* __restrict__ Wg, const float* __restrict__ Wfd,
    __hip_bfloat16* __restrict__ wgt, __hip_bfloat16* __restrict__ wfdt) {
  __shared__ float t[32][33];
  int by = blockIdx.y;
  const float* in;
  __hip_bfloat16* out;
  int C, c0;
  if (by < 32) { in = Wg; out = wgt; C = DIM; c0 = by * 32; }
  else         { in = Wfd; out = wfdt; C = HID; c0 = (by - 32) * 32; }
  int r0 = blockIdx.x * 32;
  int tx = threadIdx.x & 31, ty = threadIdx.x >> 5;
#pragma unroll
  for (int i = 0; i < 4; i++)
    t[ty + 8 * i][tx] = in[(size_t)(r0 + ty + 8 * i) * C + c0 + tx];
  __syncthreads();
#pragma unroll
  for (int i = 0; i < 4; i++)
    out[(size_t)(c0 + ty + 8 * i) * TWOD + r0 + tx] =
        __float2bfloat16(t[tx][ty + 8 * i]);
}

// GEMM1: C[M,N]=A[M,K]@Bt[N,K]^T + bg. BM=128, BN=128, BK=64 (2 halves/barrier).
// Row-remapped bf16 write into ocb.
__global__ __launch_bounds__(256) void k_gemm1(
    const __hip_bfloat16* __restrict__ A, const __hip_bfloat16* __restrict__ Bt,
    const float* __restrict__ bias, __hip_bfloat16* __restrict__ outb, int K) {
  __shared__ short lds[16384];  // A: [0,8192) 2 halves; B: [8192,16384)
  int tid = threadIdx.x;
  int lane = tid & 63, wave = tid >> 6;
  int m0 = blockIdx.y * 128, n0 = blockIdx.x * 128;
  int wr = wave >> 1, wc = wave & 1;

  f32x4 acc[4][4] = {};
  int lrow = lane >> 2, ls = lane & 3;
  int g = lane >> 4, r16 = lane & 15;

  for (int k0 = 0; k0 < K; k0 += 64) {
#pragma unroll
    for (int half = 0; half < 2; half++) {
      int kk = k0 + half * 32;
#pragma unroll
      for (int c = 0; c < 2; c++) {
        int R0 = 16 * (2 * wave + c);
        int rr = R0 + lrow;
        int slot = ls ^ SW(rr);
        GLOAD_LDS16(A + (size_t)(m0 + rr) * K + kk + slot * 8,
                    &lds[half * 4096 + R0 * 32]);
        GLOAD_LDS16(Bt + (size_t)(n0 + rr) * K + kk + slot * 8,
                    &lds[8192 + half * 4096 + R0 * 32]);
      }
    }
    __syncthreads();
#pragma unroll
    for (int half = 0; half < 2; half++) {
      bf16x8 af[4], bfr[4];
#pragma unroll
      for (int mi = 0; mi < 4; mi++) {
        int m = wr * 64 + mi * 16 + r16;
        af[mi] = *(const bf16x8*)&lds[half * 4096 + m * 32 + ((g ^ SW(m)) << 3)];
      }
#pragma unroll
      for (int ni = 0; ni < 4; ni++) {
        int n = wc * 64 + ni * 16 + r16;
        bfr[ni] =
            *(const bf16x8*)&lds[8192 + half * 4096 + n * 32 + ((g ^ SW(n)) << 3)];
      }
#pragma unroll
      for (int mi = 0; mi < 4; mi++)
#pragma unroll
        for (int ni = 0; ni < 4; ni++)
          acc[mi][ni] = __builtin_amdgcn_mfma_f32_16x16x32_bf16(
              af[mi], bfr[ni], acc[mi][ni], 0, 0, 0);
    }
    __syncthreads();
  }

#pragma unroll
  for (int mi = 0; mi < 4; mi++) {
#pragma unroll
    for (int ni = 0; ni < 4; ni++) {
#pragma unroll
      for (int r = 0; r < 4; r++) {
        int m = m0 + wr * 64 + mi * 16 + g * 4 + r;
        int n = n0 + wc * 64 + ni * 16 + r16;
        float v = acc[mi][ni][r] + bias[n];
        int om = m & (BATCH - 1);
        int on = n + ((m >> 12) << 10);
        outb[(size_t)om * TWOD + on] = __float2bfloat16(v);
      }
    }
  }
}

// GEMM2 fused with final dot: logits[m] += sum_n relu(oc@Wfd+bfd)[m,n]*Wff[n].
// BM=128, BN=64, BK=64; h never materialized.
__global__ __launch_bounds__(256) void k_gemm2_final(
    const __hip_bfloat16* __restrict__ A, const __hip_bfloat16* __restrict__ Bt,
    const float* __restrict__ bfd, const float* __restrict__ Wff,
    float* __restrict__ logits, int K) {
  __shared__ short lds[12288];  // A: [0,8192) 2 halves; B: [8192,12288)
  int tid = threadIdx.x;
  int lane = tid & 63, wave = tid >> 6;
  int m0 = blockIdx.y * 128, n0 = blockIdx.x * 64;
  int wr = wave >> 1, wc = wave & 1;

  f32x4 acc[4][2] = {};
  int lrow = lane >> 2, ls = lane & 3;
  int g = lane >> 4, r16 = lane & 15;

  for (int k0 = 0; k0 < K; k0 += 64) {
#pragma unroll
    for (int half = 0; half < 2; half++) {
      int kk = k0 + half * 32;
#pragma unroll
      for (int c = 0; c < 2; c++) {
        int R0 = 16 * (2 * wave + c);
        int rr = R0 + lrow;
        int slot = ls ^ SW(rr);
        GLOAD_LDS16(A + (size_t)(m0 + rr) * K + kk + slot * 8,
                    &lds[half * 4096 + R0 * 32]);
      }
      int RB = 16 * wave, rb = RB + lrow;
      int slotb = ls ^ SW(rb);
      GLOAD_LDS16(Bt + (size_t)(n0 + rb) * K + kk + slotb * 8,
                  &lds[8192 + half * 2048 + RB * 32]);
    }
    __syncthreads();
#pragma unroll
    for (int half = 0; half < 2; half++) {
      bf16x8 af[4], bfr[2];
#pragma unroll
      for (int mi = 0; mi < 4; mi++) {
        int m = wr * 64 + mi * 16 + r16;
        af[mi] = *(const bf16x8*)&lds[half * 4096 + m * 32 + ((g ^ SW(m)) << 3)];
      }
#pragma unroll
      for (int ni = 0; ni < 2; ni++) {
        int n = wc * 32 + ni * 16 + r16;
        bfr[ni] =
            *(const bf16x8*)&lds[8192 + half * 2048 + n * 32 + ((g ^ SW(n)) << 3)];
      }
#pragma unroll
      for (int mi = 0; mi < 4; mi++)
#pragma unroll
        for (int ni = 0; ni < 2; ni++)
          acc[mi][ni] = __builtin_amdgcn_mfma_f32_16x16x32_bf16(
              af[mi], bfr[ni], acc[mi][ni], 0, 0, 0);
    }
    __syncthreads();
  }

  int nA = n0 + wc * 32 + r16, nB = nA + 16;
  float bA = bfd[nA], bB = bfd[nB];
  float wA = Wff[nA], wB = Wff[nB];
#pragma unroll
  for (int mi = 0; mi < 4; mi++) {
#pragma unroll
    for (int r = 0; r < 4; r++) {
      float v0 = acc[mi][0][r] + bA; v0 = v0 > 0.f ? v0 : 0.f;
      float v1 = acc[mi][1][r] + bB; v1 = v1 > 0.f ? v1 : 0.f;
      float pl = v0 * wA + v1 * wB;
#pragma unroll
      for (int off = 1; off < 16; off <<= 1) pl += __shfl_xor(pl, off, 64);
      if (r16 == 0)
        atomicAdd(&logits[m0 + wr * 64 + mi * 16 + g * 4 + r], pl);
    }
  }
}

// out[b] = sigmoid(logits[b] + bff)
__global__ __launch_bounds__(256) void k_sigmoid(const float* __restrict__ logits,
                                                 const float* __restrict__ bff,
                                                 float* __restrict__ out) {
  int b = blockIdx.x * 256 + threadIdx.x;
  out[b] = 1.f / (1.f + __expf(-(logits[b] + bff[0])));
}

extern "C" void kernel_launch(void* const* d_in, const int* in_sizes, int n_in,
                              void* d_out, int out_size, void* d_ws, size_t ws_size,
                              hipStream_t stream) {
  const float* X1  = (const float*)d_in[0];
  const float* X2  = (const float*)d_in[1];
  const float* Wg  = (const float*)d_in[2];
  const float* bg  = (const float*)d_in[3];
  const float* Wfd = (const float*)d_in[4];
  const float* bfd = (const float*)d_in[5];
  const float* Wff = (const float*)d_in[6];
  const float* bff = (const float*)d_in[7];
  float* out = (float*)d_out;
  char* ws = (char*)d_ws;

  __hip_bfloat16* abf  = (__hip_bfloat16*)(ws + OFF_ABF);
  __hip_bfloat16* ocb  = (__hip_bfloat16*)(ws + OFF_OCB);
  __hip_bfloat16* wgt  = (__hip_bfloat16*)(ws + OFF_WGT);
  __hip_bfloat16* wfdt = (__hip_bfloat16*)(ws + OFF_WFDT);
  float* logits = (float*)(ws + OFF_LOG);
  float* arow   = (float*)(ws + OFF_AROW);
  float* stats  = (float*)(ws + OFF_STATS);

  k_transpose_both<<<dim3(64, 48), 256, 0, stream>>>(Wg, Wfd, wgt, wfdt);
  k_scores<<<BATCH / 4, 256, 0, stream>>>(X1, X2, abf, arow, logits);
  k_stats<<<SEQ, 256, 0, stream>>>(arow, stats);
  k_apply_y<<<BATCH, 256, 0, stream>>>(X2, arow, stats, abf);
  // GEMM1: M=8192, N=1024, K=2048 -> ocb (bf16, remapped)
  k_gemm1<<<dim3(DIM / 128, 2 * BATCH / 128), 256, 0, stream>>>(
      abf, wgt, bg, ocb, TWOD);
  // GEMM2+final: M=4096, N=512, K=2048 -> logits
  k_gemm2_final<<<dim3(HID / 64, BATCH / 128), 256, 0, stream>>>(
      ocb, wfdt, bfd, Wff, logits, TWOD);
  k_sigmoid<<<BATCH / 256, 256, 0, stream>>>(logits, bff, out);
}

// Round 7
// 205.319 us; speedup vs baseline: 4.6055x; 1.0130x over previous
//
#include <hip/hip_runtime.h>
#include <hip/hip_bf16.h>

#define BATCH 4096
#define SEQ 10
#define DIM 1024
#define TWOD 2048
#define HID 512

typedef __attribute__((ext_vector_type(8))) short bf16x8;
typedef __attribute__((ext_vector_type(4))) float f32x4;

// ---------------- workspace layout (bytes) ----------------
#define OFF_ABF   0ull                 // bf16 [8192][2048]
#define OFF_OCB   (32ull << 20)        // bf16 [4096][2048]
#define OFF_WGT   (48ull << 20)        // bf16 [1024][2048]
#define OFF_WFDT  (52ull << 20)        // bf16 [512][2048]
#define OFF_LOG   (54ull << 20)        // f32  [4096] logit accumulator
#define OFF_AROW  (62ull << 20)        // f32  [4096*16]
#define OFF_STATS (OFF_AROW + 4096ull * 16 * 4)

#define GLOAD_LDS16(g, l)                                                     \
  __builtin_amdgcn_global_load_lds(                                           \
      (const __attribute__((address_space(1))) unsigned int*)(g),             \
      (__attribute__((address_space(3))) unsigned int*)(l), 16, 0, 0)

// XOR-swizzle over the 4 16B k-slots of a 64B LDS row. sw(r)=(r+(r>>2))&3
// makes the bank-quad pattern uniform over 16-row frag reads (2-way, free).
#define SW(r) (((r) + ((r) >> 2)) & 3)

static __device__ inline void store_bf4(__hip_bfloat16* p, float4 v) {
  ushort4 u;
  __hip_bfloat16 a = __float2bfloat16(v.x), b = __float2bfloat16(v.y),
                 c = __float2bfloat16(v.z), d = __float2bfloat16(v.w);
  u.x = *(unsigned short*)&a; u.y = *(unsigned short*)&b;
  u.z = *(unsigned short*)&c; u.w = *(unsigned short*)&d;
  *(ushort4*)p = u;
}

// P1: block per batch, 4 waves; wave w owns d-slice [w*256,(w+1)*256).
// Each lane holds one float4 per X1 row (low VGPR, high occupancy).
// Produces: arow (raw y-scores), attx (bf16), X1_9/X2_9 bf16 copies; zeroes
// logits[b].
__global__ __launch_bounds__(256) void k_scores(
    const float* __restrict__ X1, const float* __restrict__ X2,
    __hip_bfloat16* __restrict__ abf, float* __restrict__ arow,
    float* __restrict__ logits) {
  int b = blockIdx.x;
  int tid = threadIdx.x;
  int wave = tid >> 6, lane = tid & 63;
  int d = wave * 256 + lane * 4;
  const float* x1b = X1 + (size_t)b * SEQ * DIM;
  const float* x2b = X2 + (size_t)b * SEQ * DIM;
  __shared__ float red[4][20];
  if (tid == 0) logits[b] = 0.f;

  float4 r[SEQ];
#pragma unroll
  for (int s = 0; s < SEQ; s++) r[s] = *(const float4*)(x1b + s * DIM + d);
  float4 x29 = *(const float4*)(x2b + 9 * DIM + d);

  // v[0..9]=px partials (X1[s]·X2[9]); v[10..18]=py[0..8] (X1[9]·X2[t]);
  // v[19]=py[9]==px[9].
  float v[20];
#pragma unroll
  for (int s = 0; s < SEQ; s++) {
    float4 a4 = r[s] * x29;
    v[s] = a4.x + a4.y + a4.z + a4.w;
  }
  v[19] = v[9];
#pragma unroll
  for (int t = 0; t < 9; t++) {
    float4 x2t = *(const float4*)(x2b + t * DIM + d);
    float4 a4 = r[9] * x2t;
    v[10 + t] = a4.x + a4.y + a4.z + a4.w;
  }
#pragma unroll
  for (int off = 1; off < 64; off <<= 1)
#pragma unroll
    for (int i = 0; i < 20; i++) v[i] += __shfl_xor(v[i], off, 64);
  if (lane < 20) red[wave][lane] = v[lane];
  __syncthreads();

  float px[SEQ], py[SEQ];
#pragma unroll
  for (int i = 0; i < SEQ; i++) {
    int j = (i == 9) ? 19 : 10 + i;
    px[i] = red[0][i] + red[1][i] + red[2][i] + red[3][i];
    py[i] = red[0][j] + red[1][j] + red[2][j] + red[3][j];
  }
  if (tid < SEQ) arow[(size_t)b * 16 + tid] = py[tid];

  float m = -1e30f;
#pragma unroll
  for (int s = 0; s < SEQ; s++) m = fmaxf(m, px[s]);
  float w[SEQ], Z = 0.f;
#pragma unroll
  for (int s = 0; s < SEQ; s++) { w[s] = __expf(px[s] - m); Z += w[s]; }
  float inv = 1.f / Z;

  __hip_bfloat16* rowx1 = abf + (size_t)b * TWOD;            // [X1_9 | atty]
  __hip_bfloat16* rowx2 = abf + (size_t)(BATCH + b) * TWOD;  // [X2_9 | attx]
  float4 ax = r[0] * w[0];
#pragma unroll
  for (int s = 1; s < SEQ; s++) ax += r[s] * w[s];
  ax *= inv;
  store_bf4(rowx2 + DIM + d, ax);  // attx
  store_bf4(rowx1 + d, r[9]);      // X1[b,9,:]
  store_bf4(rowx2 + d, x29);       // X2[b,9,:]
}

// P2: cross-batch softmax stats per t
__global__ __launch_bounds__(256) void k_stats(const float* __restrict__ arow,
                                               float* __restrict__ stats) {
  int t = blockIdx.x;
  int tid = threadIdx.x, lane = tid & 63, wave = tid >> 6;
  __shared__ float wred[4];
  float m = -1e30f;
  for (int b = tid; b < BATCH; b += 256) m = fmaxf(m, arow[(size_t)b * 16 + t]);
  for (int off = 32; off; off >>= 1) m = fmaxf(m, __shfl_down(m, off, 64));
  if (lane == 0) wred[wave] = m;
  __syncthreads();
  m = fmaxf(fmaxf(wred[0], wred[1]), fmaxf(wred[2], wred[3]));
  __syncthreads();
  float z = 0.f;
  for (int b = tid; b < BATCH; b += 256) z += __expf(arow[(size_t)b * 16 + t] - m);
  for (int off = 32; off; off >>= 1) z += __shfl_down(z, off, 64);
  if (lane == 0) wred[wave] = z;
  __syncthreads();
  if (tid == 0) {
    stats[t] = m;
    stats[16 + t] = wred[0] + wred[1] + wred[2] + wred[3];
  }
}

// P3: atty[b,d] = sum_t wy[b,t] X2[b,t,d] -> rowx1[1024+d] (bf16). L3-warm X2.
__global__ __launch_bounds__(256) void k_apply_y(const float* __restrict__ X2,
                                                 const float* __restrict__ arow,
                                                 const float* __restrict__ stats,
                                                 __hip_bfloat16* __restrict__ abf) {
  int b = blockIdx.x;
  int wave = threadIdx.x >> 6, lane = threadIdx.x & 63;
  float wy[SEQ];
#pragma unroll
  for (int t = 0; t < SEQ; t++)
    wy[t] = __expf(arow[(size_t)b * 16 + t] - stats[t]) / stats[16 + t];
  const float* x2b = X2 + (size_t)b * SEQ * DIM;
  int d = wave * 256 + lane * 4;
  float4 acc = {0.f, 0.f, 0.f, 0.f};
#pragma unroll
  for (int t = 0; t < SEQ; t++)
    acc += wy[t] * *(const float4*)(x2b + t * DIM + d);
  store_bf4(abf + (size_t)b * TWOD + DIM + d, acc);
}

// Both weight transposes in one launch. Wg: 2048x1024 -> wgt 1024x2048 (bf16);
// Wfd: 2048x512 -> wfdt 512x2048 (bf16).
__global__ __launch_bounds__(256) void k_transpose_both(
    const float* __restrict__ Wg, const float* __restrict__ Wfd,
    __hip_bfloat16* __restrict__ wgt, __hip_bfloat16* __restrict__ wfdt) {
  __shared__ float t[32][33];
  int by = blockIdx.y;
  const float* in;
  __hip_bfloat16* out;
  int C, c0;
  if (by < 32) { in = Wg; out = wgt; C = DIM; c0 = by * 32; }
  else         { in = Wfd; out = wfdt; C = HID; c0 = (by - 32) * 32; }
  int r0 = blockIdx.x * 32;
  int tx = threadIdx.x & 31, ty = threadIdx.x >> 5;
#pragma unroll
  for (int i = 0; i < 4; i++)
    t[ty + 8 * i][tx] = in[(size_t)(r0 + ty + 8 * i) * C + c0 + tx];
  __syncthreads();
#pragma unroll
  for (int i = 0; i < 4; i++)
    out[(size_t)(c0 + ty + 8 * i) * TWOD + r0 + tx] =
        __float2bfloat16(t[tx][ty + 8 * i]);
}

// GEMM1: C[M,N]=A[M,K]@Bt[N,K]^T + bg. BM=128, BN=128, BK=64 (2 halves/barrier).
// Row-remapped bf16 write into ocb.
__global__ __launch_bounds__(256) void k_gemm1(
    const __hip_bfloat16* __restrict__ A, const __hip_bfloat16* __restrict__ Bt,
    const float* __restrict__ bias, __hip_bfloat16* __restrict__ outb, int K) {
  __shared__ short lds[16384];  // A: [0,8192) 2 halves; B: [8192,16384)
  int tid = threadIdx.x;
  int lane = tid & 63, wave = tid >> 6;
  int m0 = blockIdx.y * 128, n0 = blockIdx.x * 128;
  int wr = wave >> 1, wc = wave & 1;

  f32x4 acc[4][4] = {};
  int lrow = lane >> 2, ls = lane & 3;
  int g = lane >> 4, r16 = lane & 15;

  for (int k0 = 0; k0 < K; k0 += 64) {
#pragma unroll
    for (int half = 0; half < 2; half++) {
      int kk = k0 + half * 32;
#pragma unroll
      for (int c = 0; c < 2; c++) {
        int R0 = 16 * (2 * wave + c);
        int rr = R0 + lrow;
        int slot = ls ^ SW(rr);
        GLOAD_LDS16(A + (size_t)(m0 + rr) * K + kk + slot * 8,
                    &lds[half * 4096 + R0 * 32]);
        GLOAD_LDS16(Bt + (size_t)(n0 + rr) * K + kk + slot * 8,
                    &lds[8192 + half * 4096 + R0 * 32]);
      }
    }
    __syncthreads();
#pragma unroll
    for (int half = 0; half < 2; half++) {
      bf16x8 af[4], bfr[4];
#pragma unroll
      for (int mi = 0; mi < 4; mi++) {
        int m = wr * 64 + mi * 16 + r16;
        af[mi] = *(const bf16x8*)&lds[half * 4096 + m * 32 + ((g ^ SW(m)) << 3)];
      }
#pragma unroll
      for (int ni = 0; ni < 4; ni++) {
        int n = wc * 64 + ni * 16 + r16;
        bfr[ni] =
            *(const bf16x8*)&lds[8192 + half * 4096 + n * 32 + ((g ^ SW(n)) << 3)];
      }
#pragma unroll
      for (int mi = 0; mi < 4; mi++)
#pragma unroll
        for (int ni = 0; ni < 4; ni++)
          acc[mi][ni] = __builtin_amdgcn_mfma_f32_16x16x32_bf16(
              af[mi], bfr[ni], acc[mi][ni], 0, 0, 0);
    }
    __syncthreads();
  }

#pragma unroll
  for (int mi = 0; mi < 4; mi++) {
#pragma unroll
    for (int ni = 0; ni < 4; ni++) {
#pragma unroll
      for (int r = 0; r < 4; r++) {
        int m = m0 + wr * 64 + mi * 16 + g * 4 + r;
        int n = n0 + wc * 64 + ni * 16 + r16;
        float v = acc[mi][ni][r] + bias[n];
        int om = m & (BATCH - 1);
        int on = n + ((m >> 12) << 10);
        outb[(size_t)om * TWOD + on] = __float2bfloat16(v);
      }
    }
  }
}

// GEMM2 fused with final dot: logits[m] += sum_n relu(oc@Wfd+bfd)[m,n]*Wff[n].
// BM=128, BN=64, BK=64; h never materialized.
__global__ __launch_bounds__(256) void k_gemm2_final(
    const __hip_bfloat16* __restrict__ A, const __hip_bfloat16* __restrict__ Bt,
    const float* __restrict__ bfd, const float* __restrict__ Wff,
    float* __restrict__ logits, int K) {
  __shared__ short lds[12288];  // A: [0,8192) 2 halves; B: [8192,12288)
  int tid = threadIdx.x;
  int lane = tid & 63, wave = tid >> 6;
  int m0 = blockIdx.y * 128, n0 = blockIdx.x * 64;
  int wr = wave >> 1, wc = wave & 1;

  f32x4 acc[4][2] = {};
  int lrow = lane >> 2, ls = lane & 3;
  int g = lane >> 4, r16 = lane & 15;

  for (int k0 = 0; k0 < K; k0 += 64) {
#pragma unroll
    for (int half = 0; half < 2; half++) {
      int kk = k0 + half * 32;
#pragma unroll
      for (int c = 0; c < 2; c++) {
        int R0 = 16 * (2 * wave + c);
        int rr = R0 + lrow;
        int slot = ls ^ SW(rr);
        GLOAD_LDS16(A + (size_t)(m0 + rr) * K + kk + slot * 8,
                    &lds[half * 4096 + R0 * 32]);
      }
      int RB = 16 * wave, rb = RB + lrow;
      int slotb = ls ^ SW(rb);
      GLOAD_LDS16(Bt + (size_t)(n0 + rb) * K + kk + slotb * 8,
                  &lds[8192 + half * 2048 + RB * 32]);
    }
    __syncthreads();
#pragma unroll
    for (int half = 0; half < 2; half++) {
      bf16x8 af[4], bfr[2];
#pragma unroll
      for (int mi = 0; mi < 4; mi++) {
        int m = wr * 64 + mi * 16 + r16;
        af[mi] = *(const bf16x8*)&lds[half * 4096 + m * 32 + ((g ^ SW(m)) << 3)];
      }
#pragma unroll
      for (int ni = 0; ni < 2; ni++) {
        int n = wc * 32 + ni * 16 + r16;
        bfr[ni] =
            *(const bf16x8*)&lds[8192 + half * 2048 + n * 32 + ((g ^ SW(n)) << 3)];
      }
#pragma unroll
      for (int mi = 0; mi < 4; mi++)
#pragma unroll
        for (int ni = 0; ni < 2; ni++)
          acc[mi][ni] = __builtin_amdgcn_mfma_f32_16x16x32_bf16(
              af[mi], bfr[ni], acc[mi][ni], 0, 0, 0);
    }
    __syncthreads();
  }

  int nA = n0 + wc * 32 + r16, nB = nA + 16;
  float bA = bfd[nA], bB = bfd[nB];
  float wA = Wff[nA], wB = Wff[nB];
#pragma unroll
  for (int mi = 0; mi < 4; mi++) {
#pragma unroll
    for (int r = 0; r < 4; r++) {
      float v0 = acc[mi][0][r] + bA; v0 = v0 > 0.f ? v0 : 0.f;
      float v1 = acc[mi][1][r] + bB; v1 = v1 > 0.f ? v1 : 0.f;
      float pl = v0 * wA + v1 * wB;
#pragma unroll
      for (int off = 1; off < 16; off <<= 1) pl += __shfl_xor(pl, off, 64);
      if (r16 == 0)
        atomicAdd(&logits[m0 + wr * 64 + mi * 16 + g * 4 + r], pl);
    }
  }
}

// out[b] = sigmoid(logits[b] + bff)
__global__ __launch_bounds__(256) void k_sigmoid(const float* __restrict__ logits,
                                                 const float* __restrict__ bff,
                                                 float* __restrict__ out) {
  int b = blockIdx.x * 256 + threadIdx.x;
  out[b] = 1.f / (1.f + __expf(-(logits[b] + bff[0])));
}

extern "C" void kernel_launch(void* const* d_in, const int* in_sizes, int n_in,
                              void* d_out, int out_size, void* d_ws, size_t ws_size,
                              hipStream_t stream) {
  const float* X1  = (const float*)d_in[0];
  const float* X2  = (const float*)d_in[1];
  const float* Wg  = (const float*)d_in[2];
  const float* bg  = (const float*)d_in[3];
  const float* Wfd = (const float*)d_in[4];
  const float* bfd = (const float*)d_in[5];
  const float* Wff = (const float*)d_in[6];
  const float* bff = (const float*)d_in[7];
  float* out = (float*)d_out;
  char* ws = (char*)d_ws;

  __hip_bfloat16* abf  = (__hip_bfloat16*)(ws + OFF_ABF);
  __hip_bfloat16* ocb  = (__hip_bfloat16*)(ws + OFF_OCB);
  __hip_bfloat16* wgt  = (__hip_bfloat16*)(ws + OFF_WGT);
  __hip_bfloat16* wfdt = (__hip_bfloat16*)(ws + OFF_WFDT);
  float* logits = (float*)(ws + OFF_LOG);
  float* arow   = (float*)(ws + OFF_AROW);
  float* stats  = (float*)(ws + OFF_STATS);

  k_transpose_both<<<dim3(64, 48), 256, 0, stream>>>(Wg, Wfd, wgt, wfdt);
  k_scores<<<BATCH, 256, 0, stream>>>(X1, X2, abf, arow, logits);
  k_stats<<<SEQ, 256, 0, stream>>>(arow, stats);
  k_apply_y<<<BATCH, 256, 0, stream>>>(X2, arow, stats, abf);
  // GEMM1: M=8192, N=1024, K=2048 -> ocb (bf16, remapped)
  k_gemm1<<<dim3(DIM / 128, 2 * BATCH / 128), 256, 0, stream>>>(
      abf, wgt, bg, ocb, TWOD);
  // GEMM2+final: M=4096, N=512, K=2048 -> logits
  k_gemm2_final<<<dim3(HID / 64, BATCH / 128), 256, 0, stream>>>(
      ocb, wfdt, bfd, Wff, logits, TWOD);
  k_sigmoid<<<BATCH / 256, 256, 0, stream>>>(logits, bff, out);
}

// Round 8
// 204.845 us; speedup vs baseline: 4.6161x; 1.0023x over previous
//
#include <hip/hip_runtime.h>
#include <hip/hip_bf16.h>

#define BATCH 4096
#define SEQ 10
#define DIM 1024
#define TWOD 2048
#define HID 512

typedef __attribute__((ext_vector_type(8))) short bf16x8;
typedef __attribute__((ext_vector_type(4))) float f32x4;

// ---------------- workspace layout (bytes) ----------------
#define OFF_ABF   0ull                 // bf16 [8192][2048]
#define OFF_OCB   (32ull << 20)        // bf16 [4096][2048]
#define OFF_WGT   (48ull << 20)        // bf16 [1024][2048]
#define OFF_WFDT  (52ull << 20)        // bf16 [512][2048]
#define OFF_LOG   (54ull << 20)        // f32  [4096] logit accumulator
#define OFF_AROW  (62ull << 20)        // f32  [4096*16]
#define OFF_STATS (OFF_AROW + 4096ull * 16 * 4)

#define GLOAD_LDS16(g, l)                                                     \
  __builtin_amdgcn_global_load_lds(                                           \
      (const __attribute__((address_space(1))) unsigned int*)(g),             \
      (__attribute__((address_space(3))) unsigned int*)(l), 16, 0, 0)

// XOR-swizzle over the 4 16B k-slots of a 64B LDS row.
#define SW(r) (((r) + ((r) >> 2)) & 3)

static __device__ inline void store_bf4(__hip_bfloat16* p, float4 v) {
  ushort4 u;
  __hip_bfloat16 a = __float2bfloat16(v.x), b = __float2bfloat16(v.y),
                 c = __float2bfloat16(v.z), d = __float2bfloat16(v.w);
  u.x = *(unsigned short*)&a; u.y = *(unsigned short*)&b;
  u.z = *(unsigned short*)&c; u.w = *(unsigned short*)&d;
  *(ushort4*)p = u;
}

// P1: block per batch, 4 waves; each wave OWNS 5 dot products over full rows.
//  wave0: px[0..4]=X1[s]·X2[9]   loads X1[0..4], X2[9]
//  wave1: px[5..9]=X1[s]·X2[9]   loads X1[5..9], X2[9]
//  wave2: py[0..4]=X1[9]·X2[t]   loads X2[0..4], X1[9]
//  wave3: py[5..9]=X1[9]·X2[t]   loads X2[5..9], X1[9]
// Butterfly: 6 steps x 5 values = 30 bpermutes/thread (was 120).
// attx built from register-held X1 rows (wave1 partial passed via LDS).
__global__ __launch_bounds__(256) void k_scores(
    const float* __restrict__ X1, const float* __restrict__ X2,
    __hip_bfloat16* __restrict__ abf, float* __restrict__ arow,
    float* __restrict__ logits) {
  int b = blockIdx.x;
  int tid = threadIdx.x;
  int wave = tid >> 6, lane = tid & 63;
  const float* x1b = X1 + (size_t)b * SEQ * DIM;
  const float* x2b = X2 + (size_t)b * SEQ * DIM;
  __shared__ float sc[20];        // [0..9]=px, [10..19]=py
  __shared__ float4 xch[4 * 64];  // wave1 attx partial, lane-major
  if (tid == 0) logits[b] = 0.f;

  const float* Abase;
  const float* Brow;
  if (wave == 0)      { Abase = x1b;           Brow = x2b + 9 * DIM; }
  else if (wave == 1) { Abase = x1b + 5 * DIM; Brow = x2b + 9 * DIM; }
  else if (wave == 2) { Abase = x2b;           Brow = x1b + 9 * DIM; }
  else                { Abase = x2b + 5 * DIM; Brow = x1b + 9 * DIM; }

  float4 ra[5][4], rb[4];
#pragma unroll
  for (int i = 0; i < 4; i++)
    rb[i] = *(const float4*)(Brow + i * 256 + lane * 4);
#pragma unroll
  for (int s = 0; s < 5; s++)
#pragma unroll
    for (int i = 0; i < 4; i++)
      ra[s][i] = *(const float4*)(Abase + s * DIM + i * 256 + lane * 4);

  float v[5];
#pragma unroll
  for (int s = 0; s < 5; s++) {
    float4 a4 = ra[s][0] * rb[0] + ra[s][1] * rb[1] + ra[s][2] * rb[2] +
                ra[s][3] * rb[3];
    v[s] = a4.x + a4.y + a4.z + a4.w;
  }
#pragma unroll
  for (int off = 1; off < 64; off <<= 1)
#pragma unroll
    for (int s = 0; s < 5; s++) v[s] += __shfl_xor(v[s], off, 64);

  if (lane == 0) {
    int base = wave * 5;
    sc[base + 0] = v[0]; sc[base + 1] = v[1]; sc[base + 2] = v[2];
    sc[base + 3] = v[3]; sc[base + 4] = v[4];
  }
  __syncthreads();

  if (tid < SEQ) arow[(size_t)b * 16 + tid] = sc[10 + tid];

  // softmax over px (all threads; VALU is idle anyway)
  float px[SEQ];
#pragma unroll
  for (int s = 0; s < SEQ; s++) px[s] = sc[s];
  float m = -1e30f;
#pragma unroll
  for (int s = 0; s < SEQ; s++) m = fmaxf(m, px[s]);
  float w[SEQ], Z = 0.f;
#pragma unroll
  for (int s = 0; s < SEQ; s++) { w[s] = __expf(px[s] - m); Z += w[s]; }
  float inv = 1.f / Z;

  __hip_bfloat16* rowx1 = abf + (size_t)b * TWOD;            // [X1_9 | atty]
  __hip_bfloat16* rowx2 = abf + (size_t)(BATCH + b) * TWOD;  // [X2_9 | attx]

  if (wave == 1) {
#pragma unroll
    for (int i = 0; i < 4; i++) {
      float4 pb = ra[0][i] * w[5] + ra[1][i] * w[6] + ra[2][i] * w[7] +
                  ra[3][i] * w[8] + ra[4][i] * w[9];
      xch[i * 64 + lane] = pb;
      store_bf4(rowx2 + i * 256 + lane * 4, rb[i]);  // X2[b,9,:]
    }
  } else if (wave == 2) {
#pragma unroll
    for (int i = 0; i < 4; i++)
      store_bf4(rowx1 + i * 256 + lane * 4, rb[i]);  // X1[b,9,:]
  }
  __syncthreads();
  if (wave == 0) {
#pragma unroll
    for (int i = 0; i < 4; i++) {
      float4 ax = ra[0][i] * w[0] + ra[1][i] * w[1] + ra[2][i] * w[2] +
                  ra[3][i] * w[3] + ra[4][i] * w[4];
      ax = (ax + xch[i * 64 + lane]) * inv;
      store_bf4(rowx2 + DIM + i * 256 + lane * 4, ax);  // attx
    }
  }
}

// P2: cross-batch softmax stats per t
__global__ __launch_bounds__(256) void k_stats(const float* __restrict__ arow,
                                               float* __restrict__ stats) {
  int t = blockIdx.x;
  int tid = threadIdx.x, lane = tid & 63, wave = tid >> 6;
  __shared__ float wred[4];
  float m = -1e30f;
  for (int b = tid; b < BATCH; b += 256) m = fmaxf(m, arow[(size_t)b * 16 + t]);
  for (int off = 32; off; off >>= 1) m = fmaxf(m, __shfl_down(m, off, 64));
  if (lane == 0) wred[wave] = m;
  __syncthreads();
  m = fmaxf(fmaxf(wred[0], wred[1]), fmaxf(wred[2], wred[3]));
  __syncthreads();
  float z = 0.f;
  for (int b = tid; b < BATCH; b += 256) z += __expf(arow[(size_t)b * 16 + t] - m);
  for (int off = 32; off; off >>= 1) z += __shfl_down(z, off, 64);
  if (lane == 0) wred[wave] = z;
  __syncthreads();
  if (tid == 0) {
    stats[t] = m;
    stats[16 + t] = wred[0] + wred[1] + wred[2] + wred[3];
  }
}

// P3: atty[b,d] = sum_t wy[b,t] X2[b,t,d] -> rowx1[1024+d] (bf16). L3-warm X2.
__global__ __launch_bounds__(256) void k_apply_y(const float* __restrict__ X2,
                                                 const float* __restrict__ arow,
                                                 const float* __restrict__ stats,
                                                 __hip_bfloat16* __restrict__ abf) {
  int b = blockIdx.x;
  int wave = threadIdx.x >> 6, lane = threadIdx.x & 63;
  float wy[SEQ];
#pragma unroll
  for (int t = 0; t < SEQ; t++)
    wy[t] = __expf(arow[(size_t)b * 16 + t] - stats[t]) / stats[16 + t];
  const float* x2b = X2 + (size_t)b * SEQ * DIM;
  int d = wave * 256 + lane * 4;
  float4 acc = {0.f, 0.f, 0.f, 0.f};
#pragma unroll
  for (int t = 0; t < SEQ; t++)
    acc += wy[t] * *(const float4*)(x2b + t * DIM + d);
  store_bf4(abf + (size_t)b * TWOD + DIM + d, acc);
}

// Both weight transposes in one launch.
__global__ __launch_bounds__(256) void k_transpose_both(
    const float* __restrict__ Wg, const float* __restrict__ Wfd,
    __hip_bfloat16* __restrict__ wgt, __hip_bfloat16* __restrict__ wfdt) {
  __shared__ float t[32][33];
  int by = blockIdx.y;
  const float* in;
  __hip_bfloat16* out;
  int C, c0;
  if (by < 32) { in = Wg; out = wgt; C = DIM; c0 = by * 32; }
  else         { in = Wfd; out = wfdt; C = HID; c0 = (by - 32) * 32; }
  int r0 = blockIdx.x * 32;
  int tx = threadIdx.x & 31, ty = threadIdx.x >> 5;
#pragma unroll
  for (int i = 0; i < 4; i++)
    t[ty + 8 * i][tx] = in[(size_t)(r0 + ty + 8 * i) * C + c0 + tx];
  __syncthreads();
#pragma unroll
  for (int i = 0; i < 4; i++)
    out[(size_t)(c0 + ty + 8 * i) * TWOD + r0 + tx] =
        __float2bfloat16(t[tx][ty + 8 * i]);
}

// GEMM1: C[M,N]=A[M,K]@Bt[N,K]^T + bg. BM=128, BN=128, BK=64.
__global__ __launch_bounds__(256) void k_gemm1(
    const __hip_bfloat16* __restrict__ A, const __hip_bfloat16* __restrict__ Bt,
    const float* __restrict__ bias, __hip_bfloat16* __restrict__ outb, int K) {
  __shared__ short lds[16384];
  int tid = threadIdx.x;
  int lane = tid & 63, wave = tid >> 6;
  int m0 = blockIdx.y * 128, n0 = blockIdx.x * 128;
  int wr = wave >> 1, wc = wave & 1;

  f32x4 acc[4][4] = {};
  int lrow = lane >> 2, ls = lane & 3;
  int g = lane >> 4, r16 = lane & 15;

  for (int k0 = 0; k0 < K; k0 += 64) {
#pragma unroll
    for (int half = 0; half < 2; half++) {
      int kk = k0 + half * 32;
#pragma unroll
      for (int c = 0; c < 2; c++) {
        int R0 = 16 * (2 * wave + c);
        int rr = R0 + lrow;
        int slot = ls ^ SW(rr);
        GLOAD_LDS16(A + (size_t)(m0 + rr) * K + kk + slot * 8,
                    &lds[half * 4096 + R0 * 32]);
        GLOAD_LDS16(Bt + (size_t)(n0 + rr) * K + kk + slot * 8,
                    &lds[8192 + half * 4096 + R0 * 32]);
      }
    }
    __syncthreads();
#pragma unroll
    for (int half = 0; half < 2; half++) {
      bf16x8 af[4], bfr[4];
#pragma unroll
      for (int mi = 0; mi < 4; mi++) {
        int m = wr * 64 + mi * 16 + r16;
        af[mi] = *(const bf16x8*)&lds[half * 4096 + m * 32 + ((g ^ SW(m)) << 3)];
      }
#pragma unroll
      for (int ni = 0; ni < 4; ni++) {
        int n = wc * 64 + ni * 16 + r16;
        bfr[ni] =
            *(const bf16x8*)&lds[8192 + half * 4096 + n * 32 + ((g ^ SW(n)) << 3)];
      }
#pragma unroll
      for (int mi = 0; mi < 4; mi++)
#pragma unroll
        for (int ni = 0; ni < 4; ni++)
          acc[mi][ni] = __builtin_amdgcn_mfma_f32_16x16x32_bf16(
              af[mi], bfr[ni], acc[mi][ni], 0, 0, 0);
    }
    __syncthreads();
  }

#pragma unroll
  for (int mi = 0; mi < 4; mi++) {
#pragma unroll
    for (int ni = 0; ni < 4; ni++) {
#pragma unroll
      for (int r = 0; r < 4; r++) {
        int m = m0 + wr * 64 + mi * 16 + g * 4 + r;
        int n = n0 + wc * 64 + ni * 16 + r16;
        float v = acc[mi][ni][r] + bias[n];
        int om = m & (BATCH - 1);
        int on = n + ((m >> 12) << 10);
        outb[(size_t)om * TWOD + on] = __float2bfloat16(v);
      }
    }
  }
}

// GEMM2 fused with final dot: logits[m] += sum_n relu(oc@Wfd+bfd)[m,n]*Wff[n].
__global__ __launch_bounds__(256) void k_gemm2_final(
    const __hip_bfloat16* __restrict__ A, const __hip_bfloat16* __restrict__ Bt,
    const float* __restrict__ bfd, const float* __restrict__ Wff,
    float* __restrict__ logits, int K) {
  __shared__ short lds[12288];
  int tid = threadIdx.x;
  int lane = tid & 63, wave = tid >> 6;
  int m0 = blockIdx.y * 128, n0 = blockIdx.x * 64;
  int wr = wave >> 1, wc = wave & 1;

  f32x4 acc[4][2] = {};
  int lrow = lane >> 2, ls = lane & 3;
  int g = lane >> 4, r16 = lane & 15;

  for (int k0 = 0; k0 < K; k0 += 64) {
#pragma unroll
    for (int half = 0; half < 2; half++) {
      int kk = k0 + half * 32;
#pragma unroll
      for (int c = 0; c < 2; c++) {
        int R0 = 16 * (2 * wave + c);
        int rr = R0 + lrow;
        int slot = ls ^ SW(rr);
        GLOAD_LDS16(A + (size_t)(m0 + rr) * K + kk + slot * 8,
                    &lds[half * 4096 + R0 * 32]);
      }
      int RB = 16 * wave, rb = RB + lrow;
      int slotb = ls ^ SW(rb);
      GLOAD_LDS16(Bt + (size_t)(n0 + rb) * K + kk + slotb * 8,
                  &lds[8192 + half * 2048 + RB * 32]);
    }
    __syncthreads();
#pragma unroll
    for (int half = 0; half < 2; half++) {
      bf16x8 af[4], bfr[2];
#pragma unroll
      for (int mi = 0; mi < 4; mi++) {
        int m = wr * 64 + mi * 16 + r16;
        af[mi] = *(const bf16x8*)&lds[half * 4096 + m * 32 + ((g ^ SW(m)) << 3)];
      }
#pragma unroll
      for (int ni = 0; ni < 2; ni++) {
        int n = wc * 32 + ni * 16 + r16;
        bfr[ni] =
            *(const bf16x8*)&lds[8192 + half * 2048 + n * 32 + ((g ^ SW(n)) << 3)];
      }
#pragma unroll
      for (int mi = 0; mi < 4; mi++)
#pragma unroll
        for (int ni = 0; ni < 2; ni++)
          acc[mi][ni] = __builtin_amdgcn_mfma_f32_16x16x32_bf16(
              af[mi], bfr[ni], acc[mi][ni], 0, 0, 0);
    }
    __syncthreads();
  }

  int nA = n0 + wc * 32 + r16, nB = nA + 16;
  float bA = bfd[nA], bB = bfd[nB];
  float wA = Wff[nA], wB = Wff[nB];
#pragma unroll
  for (int mi = 0; mi < 4; mi++) {
#pragma unroll
    for (int r = 0; r < 4; r++) {
      float v0 = acc[mi][0][r] + bA; v0 = v0 > 0.f ? v0 : 0.f;
      float v1 = acc[mi][1][r] + bB; v1 = v1 > 0.f ? v1 : 0.f;
      float pl = v0 * wA + v1 * wB;
#pragma unroll
      for (int off = 1; off < 16; off <<= 1) pl += __shfl_xor(pl, off, 64);
      if (r16 == 0)
        atomicAdd(&logits[m0 + wr * 64 + mi * 16 + g * 4 + r], pl);
    }
  }
}

// out[b] = sigmoid(logits[b] + bff)
__global__ __launch_bounds__(256) void k_sigmoid(const float* __restrict__ logits,
                                                 const float* __restrict__ bff,
                                                 float* __restrict__ out) {
  int b = blockIdx.x * 256 + threadIdx.x;
  out[b] = 1.f / (1.f + __expf(-(logits[b] + bff[0])));
}

extern "C" void kernel_launch(void* const* d_in, const int* in_sizes, int n_in,
                              void* d_out, int out_size, void* d_ws, size_t ws_size,
                              hipStream_t stream) {
  const float* X1  = (const float*)d_in[0];
  const float* X2  = (const float*)d_in[1];
  const float* Wg  = (const float*)d_in[2];
  const float* bg  = (const float*)d_in[3];
  const float* Wfd = (const float*)d_in[4];
  const float* bfd = (const float*)d_in[5];
  const float* Wff = (const float*)d_in[6];
  const float* bff = (const float*)d_in[7];
  float* out = (float*)d_out;
  char* ws = (char*)d_ws;

  __hip_bfloat16* abf  = (__hip_bfloat16*)(ws + OFF_ABF);
  __hip_bfloat16* ocb  = (__hip_bfloat16*)(ws + OFF_OCB);
  __hip_bfloat16* wgt  = (__hip_bfloat16*)(ws + OFF_WGT);
  __hip_bfloat16* wfdt = (__hip_bfloat16*)(ws + OFF_WFDT);
  float* logits = (float*)(ws + OFF_LOG);
  float* arow   = (float*)(ws + OFF_AROW);
  float* stats  = (float*)(ws + OFF_STATS);

  k_transpose_both<<<dim3(64, 48), 256, 0, stream>>>(Wg, Wfd, wgt, wfdt);
  k_scores<<<BATCH, 256, 0, stream>>>(X1, X2, abf, arow, logits);
  k_stats<<<SEQ, 256, 0, stream>>>(arow, stats);
  k_apply_y<<<BATCH, 256, 0, stream>>>(X2, arow, stats, abf);
  // GEMM1: M=8192, N=1024, K=2048 -> ocb (bf16, remapped)
  k_gemm1<<<dim3(DIM / 128, 2 * BATCH / 128), 256, 0, stream>>>(
      abf, wgt, bg, ocb, TWOD);
  // GEMM2+final: M=4096, N=512, K=2048 -> logits
  k_gemm2_final<<<dim3(HID / 64, BATCH / 128), 256, 0, stream>>>(
      ocb, wfdt, bfd, Wff, logits, TWOD);
  k_sigmoid<<<BATCH / 256, 256, 0, stream>>>(logits, bff, out);
}